// Round 16
// baseline (477.740 us; speedup 1.0000x reference)
//
#include <hip/hip_runtime.h>

#define TT 2048      // tokens (B*S)
#define HD 2048      // hidden
#define FD 1408      // per-expert ffn
#define SFD 5632     // shared ffn
#define NE 8         // experts
#define BM 128
#define BN 128
#define BK 32

using f32x4 = __attribute__((ext_vector_type(4))) float;
using s16x8 = __attribute__((ext_vector_type(8))) short;
typedef unsigned short us;

__device__ __forceinline__ us f2bf(float f) {
    union { float f; unsigned u; } v; v.f = f;
    unsigned r = v.u + 0x7fff + ((v.u >> 16) & 1);   // RNE
    return (us)(r >> 16);
}
__device__ __forceinline__ float bf2f(us u) {
    union { unsigned u; float f; } v; v.u = ((unsigned)u) << 16;
    return v.f;
}

__device__ __forceinline__ void gload16(const void* g, void* l) {
    __builtin_amdgcn_global_load_lds(
        (const __attribute__((address_space(1))) unsigned*)g,
        (__attribute__((address_space(3))) unsigned*)l, 16, 0, 0);
}

// 2048-element cvt tile (256 threads x 8)
__device__ __forceinline__ void cvt_tile(const float* __restrict__ src,
                                         us* __restrict__ dst, int blk) {
    size_t i = ((size_t)blk * 256 + threadIdx.x) * 8;
    float4 f0 = *(const float4*)(src + i);
    float4 f1 = *(const float4*)(src + i + 4);
    s16x8 v;
    v[0]=(short)f2bf(f0.x); v[1]=(short)f2bf(f0.y); v[2]=(short)f2bf(f0.z); v[3]=(short)f2bf(f0.w);
    v[4]=(short)f2bf(f1.x); v[5]=(short)f2bf(f1.y); v[6]=(short)f2bf(f1.z); v[7]=(short)f2bf(f1.w);
    *(s16x8*)(dst + i) = v;
}
// 8192-element cvt tile (1024 threads x 8)
__device__ __forceinline__ void cvt_tile1024(const float* __restrict__ src,
                                             us* __restrict__ dst, int blk) {
    size_t i = ((size_t)blk * 1024 + threadIdx.x) * 8;
    float4 f0 = *(const float4*)(src + i);
    float4 f1 = *(const float4*)(src + i + 4);
    s16x8 v;
    v[0]=(short)f2bf(f0.x); v[1]=(short)f2bf(f0.y); v[2]=(short)f2bf(f0.z); v[3]=(short)f2bf(f0.w);
    v[4]=(short)f2bf(f1.x); v[5]=(short)f2bf(f1.y); v[6]=(short)f2bf(f1.z); v[7]=(short)f2bf(f1.w);
    *(s16x8*)(dst + i) = v;
}

// ---- standalone cvt (fallback path) -----------------------------------------
__global__ void cvt_kernel(const float* __restrict__ x, us* __restrict__ xb) {
    cvt_tile(x, xb, blockIdx.x);
}

// ---- fused dispatch-1: router (blocks 0..511) + gateup-weight/x cvt ---------
__global__ void router_cvt_kernel(const float* __restrict__ x, const float* __restrict__ gw,
                                  const float* __restrict__ segw,
                                  int* counts, int* tlist, float* wlist, float* gateval,
                                  int* selpos,
                                  const float* __restrict__ gpw, const float* __restrict__ upw,
                                  const float* __restrict__ sgw, const float* __restrict__ suw,
                                  us* gpw_b, us* upw_b, us* sgw_b, us* suw_b, us* xb) {
    int hw = blockIdx.x;
    if (hw >= 512) {
        int i = hw - 512;
        if      (i < 11264) cvt_tile(gpw, gpw_b, i);
        else if (i < 22528) cvt_tile(upw, upw_b, i - 11264);
        else if (i < 28160) cvt_tile(sgw, sgw_b, i - 22528);
        else if (i < 33792) cvt_tile(suw, suw_b, i - 28160);
        else                cvt_tile(x,   xb,    i - 33792);
        return;
    }
    int wave = threadIdx.x >> 6;
    int lane = threadIdx.x & 63;
    int t = hw * 4 + wave;
    float acc[9];
    #pragma unroll
    for (int i = 0; i < 9; ++i) acc[i] = 0.f;
    const float* xrow = x + (size_t)t * HD;
    for (int h = lane; h < HD; h += 64) {
        float xv = xrow[h];
        #pragma unroll
        for (int e = 0; e < NE; ++e) acc[e] += xv * gw[e * HD + h];
        acc[8] += xv * segw[h];
    }
    #pragma unroll
    for (int i = 0; i < 9; ++i) {
        float v = acc[i];
        #pragma unroll
        for (int s = 32; s > 0; s >>= 1) v += __shfl_xor(v, s);
        acc[i] = v;
    }
    if (lane == 0) {
        float m = acc[0];
        #pragma unroll
        for (int e = 1; e < NE; ++e) m = fmaxf(m, acc[e]);
        float p[NE], sum = 0.f;
        #pragma unroll
        for (int e = 0; e < NE; ++e) { p[e] = expf(acc[e] - m); sum += p[e]; }
        float inv = 1.f / sum;
        int b1 = 0, b2 = -1; float v1 = p[0], v2 = -1.f;
        #pragma unroll
        for (int e = 1; e < NE; ++e) {
            if (p[e] > v1) { v2 = v1; b2 = b1; v1 = p[e]; b1 = e; }
            else if (p[e] > v2) { v2 = p[e]; b2 = e; }
        }
        v1 *= inv; v2 *= inv;
        int s1 = atomicAdd(&counts[b1], 1); tlist[b1 * TT + s1] = t; wlist[b1 * TT + s1] = v1;
        int s2 = atomicAdd(&counts[b2], 1); tlist[b2 * TT + s2] = t; wlist[b2 * TT + s2] = v2;
        selpos[2 * t]     = b1 * TT + s1;
        selpos[2 * t + 1] = b2 * TT + s2;
        gateval[t] = 1.f / (1.f + expf(-acc[8]));
    }
}

// ---- router (fallback path, standalone) -------------------------------------
__global__ void router_kernel(const float* __restrict__ x, const float* __restrict__ gw,
                              const float* __restrict__ segw,
                              int* counts, int* tlist, float* wlist, float* gateval,
                              int* selpos) {
    int wave = threadIdx.x >> 6;
    int lane = threadIdx.x & 63;
    int t = blockIdx.x * 4 + wave;
    float acc[9];
    #pragma unroll
    for (int i = 0; i < 9; ++i) acc[i] = 0.f;
    const float* xrow = x + (size_t)t * HD;
    for (int h = lane; h < HD; h += 64) {
        float xv = xrow[h];
        #pragma unroll
        for (int e = 0; e < NE; ++e) acc[e] += xv * gw[e * HD + h];
        acc[8] += xv * segw[h];
    }
    #pragma unroll
    for (int i = 0; i < 9; ++i) {
        float v = acc[i];
        #pragma unroll
        for (int s = 32; s > 0; s >>= 1) v += __shfl_xor(v, s);
        acc[i] = v;
    }
    if (lane == 0) {
        float m = acc[0];
        #pragma unroll
        for (int e = 1; e < NE; ++e) m = fmaxf(m, acc[e]);
        float p[NE], sum = 0.f;
        #pragma unroll
        for (int e = 0; e < NE; ++e) { p[e] = expf(acc[e] - m); sum += p[e]; }
        float inv = 1.f / sum;
        int b1 = 0, b2 = -1; float v1 = p[0], v2 = -1.f;
        #pragma unroll
        for (int e = 1; e < NE; ++e) {
            if (p[e] > v1) { v2 = v1; b2 = b1; v1 = p[e]; b1 = e; }
            else if (p[e] > v2) { v2 = p[e]; b2 = e; }
        }
        v1 *= inv; v2 *= inv;
        int s1 = atomicAdd(&counts[b1], 1); tlist[b1 * TT + s1] = t; wlist[b1 * TT + s1] = v1;
        int s2 = atomicAdd(&counts[b2], 1); tlist[b2 * TT + s2] = t; wlist[b2 * TT + s2] = v2;
        selpos[2 * t]     = b1 * TT + s1;
        selpos[2 * t + 1] = b2 * TT + s2;
        gateval[t] = 1.f / (1.f + expf(-acc[8]));
    }
}

__global__ void prefix_kernel(const int* counts, int* offsets) {
    if (threadIdx.x == 0) {
        int s = 0;
        for (int e = 0; e < NE; ++e) { offsets[e] = s; s += counts[e]; }
    }
}

// ---- combine (main path): out = gv*(sd0+sd1) + w0*r0 + w1*r1 ----------------
__global__ void combine_full(const int* __restrict__ selpos, const float* __restrict__ wlist,
                             const int* __restrict__ offsets, const float* __restrict__ gateval,
                             const float* __restrict__ sdpart, const us* __restrict__ robuf,
                             float* __restrict__ out) {
    int t = blockIdx.x;
    int p0 = selpos[2 * t], p1 = selpos[2 * t + 1];
    float w0 = wlist[p0], w1 = wlist[p1];
    int r0 = offsets[p0 >> 11] + (p0 & (TT - 1));
    int r1 = offsets[p1 >> 11] + (p1 & (TT - 1));
    float g = gateval[t];
    int c = threadIdx.x * 8;
    const float* s0 = sdpart + (size_t)t * HD + c;
    const float* s1 = sdpart + (size_t)TT * HD + (size_t)t * HD + c;
    s16x8 a = *(const s16x8*)(robuf + (size_t)r0 * HD + c);
    s16x8 b = *(const s16x8*)(robuf + (size_t)r1 * HD + c);
    float* op = out + (size_t)t * HD + c;
    #pragma unroll
    for (int j = 0; j < 8; ++j)
        op[j] = g * (s0[j] + s1[j]) + w0 * bf2f((us)a[j]) + w1 * bf2f((us)b[j]);
}

// ---- combine (fallback path): out += w0*r0 + w1*r1 --------------------------
__global__ void combine_add(const int* __restrict__ selpos, const float* __restrict__ wlist,
                            const int* __restrict__ offsets,
                            const us* __restrict__ robuf, float* __restrict__ out) {
    int t = blockIdx.x;
    int p0 = selpos[2 * t], p1 = selpos[2 * t + 1];
    float w0 = wlist[p0], w1 = wlist[p1];
    int r0 = offsets[p0 >> 11] + (p0 & (TT - 1));
    int r1 = offsets[p1 >> 11] + (p1 & (TT - 1));
    int c = threadIdx.x * 8;
    s16x8 a = *(const s16x8*)(robuf + (size_t)r0 * HD + c);
    s16x8 b = *(const s16x8*)(robuf + (size_t)r1 * HD + c);
    float* op = out + (size_t)t * HD + c;
    #pragma unroll
    for (int j = 0; j < 8; ++j)
        op[j] += w0 * bf2f((us)a[j]) + w1 * bf2f((us)b[j]);
}

// 1-D mega grids: BM=256. GU: 132 panels (44x[S,R,R]) x 8 m = 1056, 132/XCD.
// DN: 80 panels (16x[S,R,R,R,R]) x 8 m = 640, 80/XCD = 2 whole groups.
#define GU_TOT   1056
#define GU_CHUNK (GU_TOT / 8)
#define DN_TOT   640
#define DN_CHUNK (DN_TOT / 8)
#define GU_CVT   4224    // trailing 1024-thread cvt blocks (sdw 1408 + dpw 2816)

// =============================================================================
// gemm6: FUSED gate+up mega, tile 256x128 dual-B (BM=256 halves staged bytes
// per FLOP: 175 -> 262 FLOP/byte; staging-delivery is the measured ~13 TB/s
// ceiling). 1024 threads / 16 waves (4M x 4N), per wave 64x32 per B
// (16 frags = 64 acc regs). Staging: A 1 instr/thread (rows 0..255),
// B 1 instr/thread (waves 0-7 -> B0, 8-15 -> B1). LDS 64 KB.
// =============================================================================
__global__ __launch_bounds__(1024, 4)
void gemm6(const us* __restrict__ xb,
           const us* __restrict__ Bg_s, const us* __restrict__ Bu_s,
           const us* __restrict__ Bg_r, const us* __restrict__ Bu_r,
           us* __restrict__ Cs, us* __restrict__ Cr,
           const int* __restrict__ counts, const int* __restrict__ offsets,
           const int* __restrict__ tlist,
           const float* __restrict__ sdw_f, const float* __restrict__ dpw_f,
           us* sdw_b, us* dpw_b) {
    __shared__ s16x8 Asl[2][1024];   // 256 rows x 32k
    __shared__ s16x8 B0l[2][512];    // 128 rows x 32k
    __shared__ s16x8 B1l[2][512];

    int hw = blockIdx.x;
    if (hw >= GU_TOT) {                       // cvt backfill (1024-thread tiles)
        int i = hw - GU_TOT;
        if (i < 1408) cvt_tile1024(sdw_f, sdw_b, i);
        else          cvt_tile1024(dpw_f, dpw_b, i - 1408);
        return;
    }
    int flat = (hw & 7) * GU_CHUNK + (hw >> 3);
    int pi = flat >> 3, mt = flat & 7;
    int grpIdx = pi / 3, pos = pi % 3;
    int z, nt;
    if (pos == 0) { z = 0; nt = grpIdx; }
    else { int ri = grpIdx * 2 + (pos - 1); z = 1 + ri / 11; nt = ri % 11; }

    bool sp = (z == 0);
    int e = z - 1;
    int M = sp ? TT : counts[e];
    int n0 = nt * BN;
    int m0 = mt * 256;
    if (M == 0 || m0 >= M) return;
    int row_off = sp ? 0 : offsets[e];
    const us* B0p = sp ? Bg_s : Bg_r + (size_t)e * FD * HD;
    const us* B1p = sp ? Bu_s : Bu_r + (size_t)e * FD * HD;

    int tid = threadIdx.x;
    int lane = tid & 63, w = tid >> 6;        // w 0..15

    // A staging: thread covers tile row tid>>2 (0..255), chunk (lane&3)^((r>>1)&3)
    int srA = tid >> 2;
    int scA = (lane & 3) ^ ((srA >> 1) & 3);
    int ar = m0 + srA; if (ar > M - 1) ar = M - 1;
    size_t arow = sp ? (size_t)ar : (size_t)tlist[e * TT + ar];
    const us* aptr = xb + arow * HD + scA * 8;
    // B staging: waves 0-7 cover B0 rows [16w,+16); waves 8-15 cover B1
    int srB = 16 * (w & 7) + (lane >> 2);
    int scB = (lane & 3) ^ ((srB >> 1) & 3);
    const us* bptr = (w < 8 ? B0p : B1p) + (size_t)(n0 + srB) * HD + scB * 8;

    // wave tile: 4M x 4N -> 64 rows x 32 cols per B
    int wm = (w >> 2) * 64, wn = (w & 3) * 32;
    int grp = lane >> 4, l16 = lane & 15;

    f32x4 acc0[4][2], acc1[4][2];
    f32x4 zero = {0.f, 0.f, 0.f, 0.f};
    #pragma unroll
    for (int mi = 0; mi < 4; ++mi)
        #pragma unroll
        for (int ni = 0; ni < 2; ++ni) { acc0[mi][ni] = zero; acc1[mi][ni] = zero; }

    auto stage = [&](int buf, int k0) {
        gload16(aptr + k0, (void*)&Asl[buf][w * 64]);
        if (w < 8) gload16(bptr + k0, (void*)&B0l[buf][(w & 7) * 64]);
        else       gload16(bptr + k0, (void*)&B1l[buf][(w & 7) * 64]);
    };

    stage(0, 0);
    int cur = 0;
    const int NT = HD / BK;
    for (int kt = 0; kt < NT; ++kt) {
        __syncthreads();
        if (kt + 1 < NT) stage(cur ^ 1, (kt + 1) * BK);
        s16x8 af[4];
        #pragma unroll
        for (int mi = 0; mi < 4; ++mi) {
            int rr = wm + mi * 16 + l16;
            af[mi] = Asl[cur][rr * 4 + (grp ^ ((rr >> 1) & 3))];
        }
        #pragma unroll
        for (int ni = 0; ni < 2; ++ni) {
            int rb = wn + ni * 16 + l16;
            int slot = rb * 4 + (grp ^ ((rb >> 1) & 3));
            s16x8 b0 = B0l[cur][slot];
            #pragma unroll
            for (int mi = 0; mi < 4; ++mi)
                acc0[mi][ni] = __builtin_amdgcn_mfma_f32_16x16x32_bf16(af[mi], b0, acc0[mi][ni], 0, 0, 0);
            s16x8 b1 = B1l[cur][slot];
            #pragma unroll
            for (int mi = 0; mi < 4; ++mi)
                acc1[mi][ni] = __builtin_amdgcn_mfma_f32_16x16x32_bf16(af[mi], b1, acc1[mi][ni], 0, 0, 0);
        }
        cur ^= 1;
    }

    #pragma unroll
    for (int mi = 0; mi < 4; ++mi) {
        #pragma unroll
        for (int r_ = 0; r_ < 4; ++r_) {
            int mrow = m0 + wm + mi * 16 + (lane >> 4) * 4 + r_;
            if (mrow >= M) continue;
            #pragma unroll
            for (int ni = 0; ni < 2; ++ni) {
                int col = n0 + wn + ni * 16 + l16;
                float g = acc0[mi][ni][r_], u = acc1[mi][ni][r_];
                float val = g * u / (1.f + __expf(-g));
                if (sp) Cs[(size_t)mrow * SFD + col] = f2bf(val);
                else    Cr[(size_t)(row_off + mrow) * FD + col] = f2bf(val);
            }
        }
    }
}

// =============================================================================
// gemm_down: DOWN mega, tile 256x256 (131 FLOP/staged-byte vs 87 at 128x256).
// 1024 threads / 16 waves (4M x 4N), per wave 64x64 (16 frags). LDS 64 KB.
// z=0..1 shared-down K-slice z (K=SFD/2, C=sdpart[z] fp32); z=2..9 routed e=z-2.
// =============================================================================
__global__ __launch_bounds__(1024, 4)
void gemm_down(const us* __restrict__ Ashared, const us* __restrict__ Arouted,
               const us* __restrict__ Bshared, const us* __restrict__ Brouted,
               float* __restrict__ Cshared, us* __restrict__ Crouted,
               const int* __restrict__ counts, const int* __restrict__ offsets) {
    __shared__ s16x8 Asl[2][1024];   // 256 rows x 32k
    __shared__ s16x8 Bsl[2][1024];   // 256 rows x 32k

    int hw = blockIdx.x;
    int flat = (hw & 7) * DN_CHUNK + (hw >> 3);
    int pi = flat >> 3, mt = flat & 7;
    int grpIdx = pi / 5, pos = pi % 5;
    int z, nt;
    if (pos == 0) { z = grpIdx >> 3; nt = grpIdx & 7; }
    else { int ri = grpIdx * 4 + (pos - 1); z = 2 + (ri >> 3); nt = ri & 7; }

    bool sp = (z < 2);
    int e = z - 2;
    int M = sp ? TT : counts[e];
    int n0 = nt * 256;
    int m0 = mt * 256;
    if (M == 0 || m0 >= M) return;
    int row_off = sp ? 0 : offsets[e];
    int NT = sp ? (SFD / 2 / BK) : (FD / BK);
    int lda = sp ? SFD : FD;
    int kofs = sp ? z * (SFD / 2) : 0;
    const us* Abase = (sp ? Ashared : Arouted) + kofs;
    const us* Bbase = (sp ? Bshared : Brouted + (size_t)e * HD * FD) + kofs;

    int tid = threadIdx.x;
    int lane = tid & 63, w = tid >> 6;

    // A staging: thread covers tile row tid>>2 (0..255)
    int sr = tid >> 2;
    int sc = (lane & 3) ^ ((sr >> 1) & 3);
    int ar = m0 + sr; if (ar > M - 1) ar = M - 1;
    size_t arow = sp ? (size_t)ar : (size_t)(row_off + ar);
    const us* aptr = Abase + arow * lda + sc * 8;
    // B staging: thread covers row tid>>2
    const us* bptr = Bbase + (size_t)(n0 + sr) * lda + sc * 8;

    // wave tile: 4M x 4N -> 64 rows x 64 cols
    int wm = (w >> 2) * 64, wn = (w & 3) * 64;
    int grp = lane >> 4, l16 = lane & 15;

    f32x4 acc[4][4];
    f32x4 zero = {0.f, 0.f, 0.f, 0.f};
    #pragma unroll
    for (int mi = 0; mi < 4; ++mi)
        #pragma unroll
        for (int ni = 0; ni < 4; ++ni) acc[mi][ni] = zero;

    auto stage = [&](int buf, int k0) {
        gload16(aptr + k0, (void*)&Asl[buf][w * 64]);
        gload16(bptr + k0, (void*)&Bsl[buf][w * 64]);
    };

    stage(0, 0);
    int cur = 0;
    for (int kt = 0; kt < NT; ++kt) {
        __syncthreads();
        if (kt + 1 < NT) stage(cur ^ 1, (kt + 1) * BK);
        s16x8 af[4];
        #pragma unroll
        for (int mi = 0; mi < 4; ++mi) {
            int rr = wm + mi * 16 + l16;
            af[mi] = Asl[cur][rr * 4 + (grp ^ ((rr >> 1) & 3))];
        }
        #pragma unroll
        for (int ni = 0; ni < 4; ++ni) {
            int rb = wn + ni * 16 + l16;
            s16x8 bf = Bsl[cur][rb * 4 + (grp ^ ((rb >> 1) & 3))];
            #pragma unroll
            for (int mi = 0; mi < 4; ++mi)
                acc[mi][ni] = __builtin_amdgcn_mfma_f32_16x16x32_bf16(af[mi], bf, acc[mi][ni], 0, 0, 0);
        }
        cur ^= 1;
    }

    #pragma unroll
    for (int mi = 0; mi < 4; ++mi) {
        #pragma unroll
        for (int r_ = 0; r_ < 4; ++r_) {
            int mrow = m0 + wm + mi * 16 + (lane >> 4) * 4 + r_;
            if (mrow >= M) continue;
            #pragma unroll
            for (int ni = 0; ni < 4; ++ni) {
                int col = n0 + wn + ni * 16 + l16;
                float v = acc[mi][ni][r_];
                if (sp) Cshared[(size_t)z * TT * HD + (size_t)mrow * HD + col] = v;
                else    Crouted[(size_t)(row_off + mrow) * HD + col] = f2bf(v);
            }
        }
    }
}

// =============================================================================
// gemm4 (fallback path, round-5 proven): fp32 B staged via global_load_lds.
// =============================================================================
__device__ __forceinline__ unsigned cvt2(float a, float b) {
    union { float f; unsigned u; } va, vb; va.f = a; vb.f = b;
    unsigned ra = va.u + 0x8000u, rb = vb.u + 0x8000u;
    return (rb & 0xffff0000u) | (ra >> 16);
}
__device__ __forceinline__ s16x8 pack8(f32x4 h0, f32x4 h1) {
    union { unsigned u[4]; s16x8 s; } r;
    r.u[0] = cvt2(h0[0], h0[1]); r.u[1] = cvt2(h0[2], h0[3]);
    r.u[2] = cvt2(h1[0], h1[1]); r.u[3] = cvt2(h1[2], h1[3]);
    return r.s;
}

template<int EPI, bool GATHER>
__global__ __launch_bounds__(256, 2)
void gemm4(const us* __restrict__ A, int lda,
           const float* __restrict__ B, size_t eStrideB, int ldb, int K,
           int Mfixed, const int* __restrict__ counts, const int* __restrict__ offsets,
           const int* __restrict__ tlist, const float* __restrict__ wlist,
           us* __restrict__ C, int ldc,
           const float* __restrict__ gateval, float* __restrict__ out, int ldout) {
    __shared__ s16x8 As[3][512];
    __shared__ f32x4 Bs[3][1024];

    int e = blockIdx.z;
    int M = counts ? counts[e] : Mfixed;
    int n0 = blockIdx.x * BN;
    int m0 = blockIdx.y * BM;
    if (M == 0 || m0 >= M) return;
    int row_off = offsets ? offsets[e] : 0;
    const float* Bp = B + (size_t)e * eStrideB;

    int tid = threadIdx.x;
    int lane = tid & 63, w = tid >> 6;

    const us* aptr[2];
    #pragma unroll
    for (int j = 0; j < 2; ++j) {
        int r = 32 * w + 16 * j + (lane >> 2);
        int c = (lane & 3) ^ (r & 3);
        int ar = m0 + r; if (ar > M - 1) ar = M - 1;
        size_t grow;
        if constexpr (GATHER) grow = (size_t)tlist[e * TT + ar];
        else                  grow = (size_t)(row_off + ar);
        aptr[j] = A + grow * (size_t)lda + c * 8;
    }
    const float* bptr[4];
    #pragma unroll
    for (int j = 0; j < 4; ++j) {
        int r = 32 * w + 8 * j + (lane >> 3);
        int c = (lane & 7) ^ (r & 7);
        bptr[j] = Bp + (size_t)(n0 + r) * ldb + c * 4;
    }

    int wm = (w >> 1) * 64, wn = (w & 1) * 64;
    int grp = lane >> 4, l16 = lane & 15;

    f32x4 acc[4][4];
    f32x4 zero = {0.f, 0.f, 0.f, 0.f};
    #pragma unroll
    for (int mi = 0; mi < 4; ++mi)
        #pragma unroll
        for (int ni = 0; ni < 4; ++ni) acc[mi][ni] = zero;

    auto stage = [&](int buf, int k0) {
        #pragma unroll
        for (int j = 0; j < 2; ++j)
            gload16(aptr[j] + k0, (void*)&As[buf][(32 * w + 16 * j) * 4]);
        #pragma unroll
        for (int j = 0; j < 4; ++j)
            gload16(bptr[j] + k0, (void*)&Bs[buf][(32 * w + 8 * j) * 8]);
    };

    int NT = K / BK;
    stage(0, 0);
    stage(1, BK);
    for (int kt = 0; kt < NT; ++kt) {
        int cur = kt % 3;
        __builtin_amdgcn_s_barrier();
        if (kt + 2 < NT) {
            stage((kt + 2) % 3, (kt + 2) * BK);
            asm volatile("s_waitcnt vmcnt(12)" ::: "memory");
        } else if (kt + 1 < NT) {
            asm volatile("s_waitcnt vmcnt(6)" ::: "memory");
        } else {
            asm volatile("s_waitcnt vmcnt(0)" ::: "memory");
        }
        s16x8 af[4];
        #pragma unroll
        for (int mi = 0; mi < 4; ++mi) {
            int rr = wm + mi * 16 + l16;
            af[mi] = As[cur][rr * 4 + (grp ^ (rr & 3))];
        }
        #pragma unroll
        for (int ni = 0; ni < 4; ++ni) {
            int rb = wn + ni * 16 + l16;
            int s0 = (2 * grp) ^ (rb & 7);
            f32x4 h0 = Bs[cur][rb * 8 + s0];
            f32x4 h1 = Bs[cur][rb * 8 + (s0 ^ 1)];
            s16x8 bfr = pack8(h0, h1);
            #pragma unroll
            for (int mi = 0; mi < 4; ++mi)
                acc[mi][ni] = __builtin_amdgcn_mfma_f32_16x16x32_bf16(af[mi], bfr, acc[mi][ni], 0, 0, 0);
        }
    }

    #pragma unroll
    for (int mi = 0; mi < 4; ++mi) {
        #pragma unroll
        for (int r_ = 0; r_ < 4; ++r_) {
            int mrow = m0 + wm + mi * 16 + (lane >> 4) * 4 + r_;
            if (mrow >= M) continue;
            #pragma unroll
            for (int ni = 0; ni < 4; ++ni) {
                int col = n0 + wn + ni * 16 + l16;
                float v = acc[mi][ni][r_];
                if constexpr (EPI == 0) {
                    C[(size_t)(row_off + mrow) * ldc + col] = f2bf(v);
                } else if constexpr (EPI == 1) {
                    size_t idx = (size_t)(row_off + mrow) * ldc + col;
                    float g = bf2f(C[idx]);
                    C[idx] = f2bf(g * v / (1.f + __expf(-g)));
                } else if constexpr (EPI == 2) {
                    int tok = tlist[e * TT + mrow]; float wv = wlist[e * TT + mrow];
                    atomicAdd(out + (size_t)tok * ldout + col, wv * v);
                } else {
                    out[(size_t)mrow * ldout + col] = gateval[mrow] * v;
                }
            }
        }
    }
}

extern "C" void kernel_launch(void* const* d_in, const int* in_sizes, int n_in,
                              void* d_out, int out_size, void* d_ws, size_t ws_size,
                              hipStream_t stream) {
    const float* x    = (const float*)d_in[0];
    const float* gw   = (const float*)d_in[1];
    const float* gpw  = (const float*)d_in[2];
    const float* upw  = (const float*)d_in[3];
    const float* dpw  = (const float*)d_in[4];
    const float* sgw  = (const float*)d_in[5];
    const float* suw  = (const float*)d_in[6];
    const float* sdw  = (const float*)d_in[7];
    const float* segw = (const float*)d_in[8];
    float* out = (float*)d_out;
    char* ws = (char*)d_ws;

    int*   counts  = (int*)(ws + 0);
    int*   offsets = (int*)(ws + 64);
    int*   tlist   = (int*)(ws + 256);
    float* wlist   = (float*)(ws + 65792);
    float* gateval = (float*)(ws + 131328);
    int*   selpos  = (int*)(ws + 139520);

    hipMemsetAsync(counts, 0, 64, stream);

    // ---------------- main path: fused cvt + mega-dispatches -------------------
    size_t need_main = 301203456ull;
    if (ws_size >= need_main) {
        us* xb     = (us*)(ws + 262144);          //   8.4 MB
        us* gpw_b  = (us*)(ws + 8650752);         //  46.1 MB
        us* upw_b  = (us*)(ws + 54788096);        //  46.1 MB
        us* dpw_b  = (us*)(ws + 100925440);       //  46.1 MB
        us* sgw_b  = (us*)(ws + 147062784);       //  23.1 MB
        us* suw_b  = (us*)(ws + 170131456);       //  23.1 MB
        us* sdw_b  = (us*)(ws + 193200128);       //  23.1 MB
        us* gbuf_s = (us*)(ws + 216268800);       //  23.1 MB
        us* gbuf_r = (us*)(ws + 239337472);       //  11.5 MB
        us* robuf  = (us*)(ws + 250871808);       //  16.8 MB
        float* sdpart = (float*)(ws + 267649024); //  33.6 MB (2 fp32 partials)

        // dispatch 1: router + x/gateup-weight cvt
        router_cvt_kernel<<<dim3(512 + 35840), 256, 0, stream>>>(
            x, gw, segw, counts, tlist, wlist, gateval, selpos,
            gpw, upw, sgw, suw, gpw_b, upw_b, sgw_b, suw_b, xb);
        prefix_kernel<<<dim3(1), 64, 0, stream>>>(counts, offsets);

        // dispatch 2: FUSED gate+up mega (BM=256, 16 waves) + down-weight cvt
        gemm6<<<dim3(GU_TOT + GU_CVT), 1024, 0, stream>>>(
            xb, sgw_b, suw_b, gpw_b, upw_b, gbuf_s, gbuf_r, counts, offsets, tlist,
            sdw, dpw, sdw_b, dpw_b);
        // dispatch 3: DOWN mega (256x256, 16 waves)
        gemm_down<<<dim3(DN_TOT), 1024, 0, stream>>>(
            gbuf_s, gbuf_r, sdw_b, dpw_b, sdpart, robuf, counts, offsets);

        combine_full<<<dim3(TT), 256, 0, stream>>>(selpos, wlist, offsets, gateval, sdpart, robuf, out);
        return;
    }

    // ---------------- fallback path (round-5, proven) --------------------------
    us* xb    = (us*)(ws + 155904);
    us* gbuf  = (us*)(ws + 8544512);
    us* robuf = (us*)(ws + 20078848);
    size_t need_fb = 20078848 + (size_t)4096 * HD * 2;

    router_kernel<<<dim3(TT / 4), 256, 0, stream>>>(x, gw, segw, counts, tlist, wlist, gateval, selpos);
    prefix_kernel<<<dim3(1), 64, 0, stream>>>(counts, offsets);
    cvt_kernel<<<dim3(TT * HD / 2048), 256, 0, stream>>>(x, xb);

    gemm4<0, false><<<dim3(SFD / BN, TT / BM, 1), 256, 0, stream>>>(
        xb, HD, sgw, 0, HD, HD, TT, nullptr, nullptr, nullptr, nullptr, gbuf, SFD, nullptr, nullptr, 0);
    gemm4<1, false><<<dim3(SFD / BN, TT / BM, 1), 256, 0, stream>>>(
        xb, HD, suw, 0, HD, HD, TT, nullptr, nullptr, nullptr, nullptr, gbuf, SFD, nullptr, nullptr, 0);
    gemm4<3, false><<<dim3(HD / BN, TT / BM, 1), 256, 0, stream>>>(
        gbuf, SFD, sdw, 0, SFD, SFD, TT, nullptr, nullptr, nullptr, nullptr, nullptr, 0, gateval, out, HD);

    gemm4<0, true><<<dim3(FD / BN, TT / BM, NE), 256, 0, stream>>>(
        xb, HD, gpw, (size_t)FD * HD, HD, HD, 0, counts, offsets, tlist, nullptr, gbuf, FD, nullptr, nullptr, 0);
    gemm4<1, true><<<dim3(FD / BN, TT / BM, NE), 256, 0, stream>>>(
        xb, HD, upw, (size_t)FD * HD, HD, HD, 0, counts, offsets, tlist, nullptr, gbuf, FD, nullptr, nullptr, 0);

    if (ws_size >= need_fb) {
        gemm4<0, false><<<dim3(HD / BN, TT / BM, NE), 256, 0, stream>>>(
            gbuf, FD, dpw, (size_t)HD * FD, FD, FD, 0, counts, offsets, nullptr, nullptr, robuf, HD, nullptr, nullptr, 0);
        combine_add<<<dim3(TT), 256, 0, stream>>>(selpos, wlist, offsets, robuf, out);
    } else {
        gemm4<2, false><<<dim3(HD / BN, TT / BM, NE), 256, 0, stream>>>(
            gbuf, FD, dpw, (size_t)HD * FD, FD, FD, 0, counts, offsets, tlist, wlist, nullptr, 0, nullptr, out, HD);
    }
}

// Round 17
// 445.067 us; speedup vs baseline: 1.0734x; 1.0734x over previous
//
#include <hip/hip_runtime.h>

#define TT 2048      // tokens (B*S)
#define HD 2048      // hidden
#define FD 1408      // per-expert ffn
#define SFD 5632     // shared ffn
#define NE 8         // experts
#define BM 128
#define BN 128
#define BK 32

using f32x4 = __attribute__((ext_vector_type(4))) float;
using s16x8 = __attribute__((ext_vector_type(8))) short;
typedef unsigned short us;

__device__ __forceinline__ us f2bf(float f) {
    union { float f; unsigned u; } v; v.f = f;
    unsigned r = v.u + 0x7fff + ((v.u >> 16) & 1);   // RNE
    return (us)(r >> 16);
}
__device__ __forceinline__ float bf2f(us u) {
    union { unsigned u; float f; } v; v.u = ((unsigned)u) << 16;
    return v.f;
}

__device__ __forceinline__ void gload16(const void* g, void* l) {
    __builtin_amdgcn_global_load_lds(
        (const __attribute__((address_space(1))) unsigned*)g,
        (__attribute__((address_space(3))) unsigned*)l, 16, 0, 0);
}

// 2048-element cvt tile (256 threads x 8)
__device__ __forceinline__ void cvt_tile(const float* __restrict__ src,
                                         us* __restrict__ dst, int blk) {
    size_t i = ((size_t)blk * 256 + threadIdx.x) * 8;
    float4 f0 = *(const float4*)(src + i);
    float4 f1 = *(const float4*)(src + i + 4);
    s16x8 v;
    v[0]=(short)f2bf(f0.x); v[1]=(short)f2bf(f0.y); v[2]=(short)f2bf(f0.z); v[3]=(short)f2bf(f0.w);
    v[4]=(short)f2bf(f1.x); v[5]=(short)f2bf(f1.y); v[6]=(short)f2bf(f1.z); v[7]=(short)f2bf(f1.w);
    *(s16x8*)(dst + i) = v;
}
// 4096-element cvt tile (512 threads x 8)
__device__ __forceinline__ void cvt_tile512(const float* __restrict__ src,
                                            us* __restrict__ dst, int blk) {
    size_t i = ((size_t)blk * 512 + threadIdx.x) * 8;
    float4 f0 = *(const float4*)(src + i);
    float4 f1 = *(const float4*)(src + i + 4);
    s16x8 v;
    v[0]=(short)f2bf(f0.x); v[1]=(short)f2bf(f0.y); v[2]=(short)f2bf(f0.z); v[3]=(short)f2bf(f0.w);
    v[4]=(short)f2bf(f1.x); v[5]=(short)f2bf(f1.y); v[6]=(short)f2bf(f1.z); v[7]=(short)f2bf(f1.w);
    *(s16x8*)(dst + i) = v;
}

// ---- standalone cvt (fallback path) -----------------------------------------
__global__ void cvt_kernel(const float* __restrict__ x, us* __restrict__ xb) {
    cvt_tile(x, xb, blockIdx.x);
}

// ---- fused dispatch-1: router (blocks 0..511) + gateup-weight/x cvt ---------
__global__ void router_cvt_kernel(const float* __restrict__ x, const float* __restrict__ gw,
                                  const float* __restrict__ segw,
                                  int* counts, int* tlist, float* wlist, float* gateval,
                                  int* selpos,
                                  const float* __restrict__ gpw, const float* __restrict__ upw,
                                  const float* __restrict__ sgw, const float* __restrict__ suw,
                                  us* gpw_b, us* upw_b, us* sgw_b, us* suw_b, us* xb) {
    int hw = blockIdx.x;
    if (hw >= 512) {
        int i = hw - 512;
        if      (i < 11264) cvt_tile(gpw, gpw_b, i);
        else if (i < 22528) cvt_tile(upw, upw_b, i - 11264);
        else if (i < 28160) cvt_tile(sgw, sgw_b, i - 22528);
        else if (i < 33792) cvt_tile(suw, suw_b, i - 28160);
        else                cvt_tile(x,   xb,    i - 33792);
        return;
    }
    int wave = threadIdx.x >> 6;
    int lane = threadIdx.x & 63;
    int t = hw * 4 + wave;
    float acc[9];
    #pragma unroll
    for (int i = 0; i < 9; ++i) acc[i] = 0.f;
    const float* xrow = x + (size_t)t * HD;
    for (int h = lane; h < HD; h += 64) {
        float xv = xrow[h];
        #pragma unroll
        for (int e = 0; e < NE; ++e) acc[e] += xv * gw[e * HD + h];
        acc[8] += xv * segw[h];
    }
    #pragma unroll
    for (int i = 0; i < 9; ++i) {
        float v = acc[i];
        #pragma unroll
        for (int s = 32; s > 0; s >>= 1) v += __shfl_xor(v, s);
        acc[i] = v;
    }
    if (lane == 0) {
        float m = acc[0];
        #pragma unroll
        for (int e = 1; e < NE; ++e) m = fmaxf(m, acc[e]);
        float p[NE], sum = 0.f;
        #pragma unroll
        for (int e = 0; e < NE; ++e) { p[e] = expf(acc[e] - m); sum += p[e]; }
        float inv = 1.f / sum;
        int b1 = 0, b2 = -1; float v1 = p[0], v2 = -1.f;
        #pragma unroll
        for (int e = 1; e < NE; ++e) {
            if (p[e] > v1) { v2 = v1; b2 = b1; v1 = p[e]; b1 = e; }
            else if (p[e] > v2) { v2 = p[e]; b2 = e; }
        }
        v1 *= inv; v2 *= inv;
        int s1 = atomicAdd(&counts[b1], 1); tlist[b1 * TT + s1] = t; wlist[b1 * TT + s1] = v1;
        int s2 = atomicAdd(&counts[b2], 1); tlist[b2 * TT + s2] = t; wlist[b2 * TT + s2] = v2;
        selpos[2 * t]     = b1 * TT + s1;
        selpos[2 * t + 1] = b2 * TT + s2;
        gateval[t] = 1.f / (1.f + expf(-acc[8]));
    }
}

// ---- router (fallback path, standalone) -------------------------------------
__global__ void router_kernel(const float* __restrict__ x, const float* __restrict__ gw,
                              const float* __restrict__ segw,
                              int* counts, int* tlist, float* wlist, float* gateval,
                              int* selpos) {
    int wave = threadIdx.x >> 6;
    int lane = threadIdx.x & 63;
    int t = blockIdx.x * 4 + wave;
    float acc[9];
    #pragma unroll
    for (int i = 0; i < 9; ++i) acc[i] = 0.f;
    const float* xrow = x + (size_t)t * HD;
    for (int h = lane; h < HD; h += 64) {
        float xv = xrow[h];
        #pragma unroll
        for (int e = 0; e < NE; ++e) acc[e] += xv * gw[e * HD + h];
        acc[8] += xv * segw[h];
    }
    #pragma unroll
    for (int i = 0; i < 9; ++i) {
        float v = acc[i];
        #pragma unroll
        for (int s = 32; s > 0; s >>= 1) v += __shfl_xor(v, s);
        acc[i] = v;
    }
    if (lane == 0) {
        float m = acc[0];
        #pragma unroll
        for (int e = 1; e < NE; ++e) m = fmaxf(m, acc[e]);
        float p[NE], sum = 0.f;
        #pragma unroll
        for (int e = 0; e < NE; ++e) { p[e] = expf(acc[e] - m); sum += p[e]; }
        float inv = 1.f / sum;
        int b1 = 0, b2 = -1; float v1 = p[0], v2 = -1.f;
        #pragma unroll
        for (int e = 1; e < NE; ++e) {
            if (p[e] > v1) { v2 = v1; b2 = b1; v1 = p[e]; b1 = e; }
            else if (p[e] > v2) { v2 = p[e]; b2 = e; }
        }
        v1 *= inv; v2 *= inv;
        int s1 = atomicAdd(&counts[b1], 1); tlist[b1 * TT + s1] = t; wlist[b1 * TT + s1] = v1;
        int s2 = atomicAdd(&counts[b2], 1); tlist[b2 * TT + s2] = t; wlist[b2 * TT + s2] = v2;
        selpos[2 * t]     = b1 * TT + s1;
        selpos[2 * t + 1] = b2 * TT + s2;
        gateval[t] = 1.f / (1.f + expf(-acc[8]));
    }
}

__global__ void prefix_kernel(const int* counts, int* offsets) {
    if (threadIdx.x == 0) {
        int s = 0;
        for (int e = 0; e < NE; ++e) { offsets[e] = s; s += counts[e]; }
    }
}

// ---- combine (main path): out = gv*(sd0+sd1) + w0*r0 + w1*r1 ----------------
__global__ void combine_full(const int* __restrict__ selpos, const float* __restrict__ wlist,
                             const int* __restrict__ offsets, const float* __restrict__ gateval,
                             const float* __restrict__ sdpart, const us* __restrict__ robuf,
                             float* __restrict__ out) {
    int t = blockIdx.x;
    int p0 = selpos[2 * t], p1 = selpos[2 * t + 1];
    float w0 = wlist[p0], w1 = wlist[p1];
    int r0 = offsets[p0 >> 11] + (p0 & (TT - 1));
    int r1 = offsets[p1 >> 11] + (p1 & (TT - 1));
    float g = gateval[t];
    int c = threadIdx.x * 8;
    const float* s0 = sdpart + (size_t)t * HD + c;
    const float* s1 = sdpart + (size_t)TT * HD + (size_t)t * HD + c;
    s16x8 a = *(const s16x8*)(robuf + (size_t)r0 * HD + c);
    s16x8 b = *(const s16x8*)(robuf + (size_t)r1 * HD + c);
    float* op = out + (size_t)t * HD + c;
    #pragma unroll
    for (int j = 0; j < 8; ++j)
        op[j] = g * (s0[j] + s1[j]) + w0 * bf2f((us)a[j]) + w1 * bf2f((us)b[j]);
}

// ---- combine (fallback path): out += w0*r0 + w1*r1 --------------------------
__global__ void combine_add(const int* __restrict__ selpos, const float* __restrict__ wlist,
                            const int* __restrict__ offsets,
                            const us* __restrict__ robuf, float* __restrict__ out) {
    int t = blockIdx.x;
    int p0 = selpos[2 * t], p1 = selpos[2 * t + 1];
    float w0 = wlist[p0], w1 = wlist[p1];
    int r0 = offsets[p0 >> 11] + (p0 & (TT - 1));
    int r1 = offsets[p1 >> 11] + (p1 & (TT - 1));
    int c = threadIdx.x * 8;
    s16x8 a = *(const s16x8*)(robuf + (size_t)r0 * HD + c);
    s16x8 b = *(const s16x8*)(robuf + (size_t)r1 * HD + c);
    float* op = out + (size_t)t * HD + c;
    #pragma unroll
    for (int j = 0; j < 8; ++j)
        op[j] += w0 * bf2f((us)a[j]) + w1 * bf2f((us)b[j]);
}

// 1-D mega grids (r9/r11 decode, unchanged)
#define GU_TOT   2112
#define GU_CHUNK (GU_TOT / 8)
#define DN_TOT   1280
#define DN_CHUNK (DN_TOT / 8)
#define GU_CVT   8448    // trailing 512-thread cvt blocks (sdw 2816 + dpw 5632)

// =============================================================================
// gemm6: FUSED gate+up mega, 512 threads / 8 waves (r15) + 3-LDS-buffer
// depth-2 counted-vmcnt pipeline (r5-proven schedule). Per thread 3 stage
// instrs/tile -> vmcnt(6)=stage(kt) landed while stage(kt+1) stays in flight
// (~2 K-steps of latency cover). LDS 72 KB -> 2 blocks x 8 waves = 16 waves/CU
// (same occupancy as r15; this isolates pipeline depth at high occupancy).
// =============================================================================
__global__ __launch_bounds__(512, 4)
void gemm6(const us* __restrict__ xb,
           const us* __restrict__ Bg_s, const us* __restrict__ Bu_s,
           const us* __restrict__ Bg_r, const us* __restrict__ Bu_r,
           us* __restrict__ Cs, us* __restrict__ Cr,
           const int* __restrict__ counts, const int* __restrict__ offsets,
           const int* __restrict__ tlist,
           const float* __restrict__ sdw_f, const float* __restrict__ dpw_f,
           us* sdw_b, us* dpw_b) {
    __shared__ s16x8 Asl[3][512];
    __shared__ s16x8 B0l[3][512];
    __shared__ s16x8 B1l[3][512];

    int hw = blockIdx.x;
    if (hw >= GU_TOT) {                       // cvt backfill (512-thread tiles)
        int i = hw - GU_TOT;
        if (i < 2816) cvt_tile512(sdw_f, sdw_b, i);
        else          cvt_tile512(dpw_f, dpw_b, i - 2816);
        return;
    }
    int flat = (hw & 7) * GU_CHUNK + (hw >> 3);
    int pi = flat >> 4, mt = flat & 15;
    int grpIdx = pi / 3, pos = pi % 3;
    int z, nt;
    if (pos == 0) { z = 0; nt = grpIdx; }
    else { int ri = grpIdx * 2 + (pos - 1); z = 1 + ri / 11; nt = ri % 11; }

    bool sp = (z == 0);
    int e = z - 1;
    int M = sp ? TT : counts[e];
    int n0 = nt * BN;
    int m0 = mt * BM;
    if (M == 0 || m0 >= M) return;
    int row_off = sp ? 0 : offsets[e];
    const us* B0p = sp ? Bg_s : Bg_r + (size_t)e * FD * HD;
    const us* B1p = sp ? Bu_s : Bu_r + (size_t)e * FD * HD;

    int tid = threadIdx.x;
    int lane = tid & 63, w = tid >> 6;

    // staging: thread covers tile row tid>>2, chunk (lane&3)^((row>>1)&3)
    int sr = tid >> 2;
    int sc = (lane & 3) ^ ((sr >> 1) & 3);
    int ar = m0 + sr; if (ar > M - 1) ar = M - 1;
    size_t arow = sp ? (size_t)ar : (size_t)tlist[e * TT + ar];
    const us* aptr  = xb  + arow * HD + sc * 8;
    const us* b0ptr = B0p + (size_t)(n0 + sr) * HD + sc * 8;
    const us* b1ptr = B1p + (size_t)(n0 + sr) * HD + sc * 8;

    // wave tile: 2M x 4N -> per wave 64 rows x 32 cols
    int wm = (w >> 2) * 64, wn = (w & 3) * 32;
    int grp = lane >> 4, l16 = lane & 15;

    f32x4 acc0[4][2], acc1[4][2];
    f32x4 zero = {0.f, 0.f, 0.f, 0.f};
    #pragma unroll
    for (int mi = 0; mi < 4; ++mi)
        #pragma unroll
        for (int ni = 0; ni < 2; ++ni) { acc0[mi][ni] = zero; acc1[mi][ni] = zero; }

    auto stage = [&](int buf, int k0) {
        gload16(aptr  + k0, (void*)&Asl[buf][16 * w * 4]);
        gload16(b0ptr + k0, (void*)&B0l[buf][16 * w * 4]);
        gload16(b1ptr + k0, (void*)&B1l[buf][16 * w * 4]);
    };

    const int NT = HD / BK;
    stage(0, 0);
    stage(1, BK);
    for (int kt = 0; kt < NT; ++kt) {
        int cur = kt % 3;
        __builtin_amdgcn_s_barrier();
        if (kt + 2 < NT) {
            stage((kt + 2) % 3, (kt + 2) * BK);
            asm volatile("s_waitcnt vmcnt(6)" ::: "memory");
        } else if (kt + 1 < NT) {
            asm volatile("s_waitcnt vmcnt(3)" ::: "memory");
        } else {
            asm volatile("s_waitcnt vmcnt(0)" ::: "memory");
        }
        s16x8 af[4];
        #pragma unroll
        for (int mi = 0; mi < 4; ++mi) {
            int rr = wm + mi * 16 + l16;
            af[mi] = Asl[cur][rr * 4 + (grp ^ ((rr >> 1) & 3))];
        }
        #pragma unroll
        for (int ni = 0; ni < 2; ++ni) {
            int rb = wn + ni * 16 + l16;
            int slot = rb * 4 + (grp ^ ((rb >> 1) & 3));
            s16x8 b0 = B0l[cur][slot];
            #pragma unroll
            for (int mi = 0; mi < 4; ++mi)
                acc0[mi][ni] = __builtin_amdgcn_mfma_f32_16x16x32_bf16(af[mi], b0, acc0[mi][ni], 0, 0, 0);
            s16x8 b1 = B1l[cur][slot];
            #pragma unroll
            for (int mi = 0; mi < 4; ++mi)
                acc1[mi][ni] = __builtin_amdgcn_mfma_f32_16x16x32_bf16(af[mi], b1, acc1[mi][ni], 0, 0, 0);
        }
    }

    #pragma unroll
    for (int mi = 0; mi < 4; ++mi) {
        #pragma unroll
        for (int r_ = 0; r_ < 4; ++r_) {
            int mrow = m0 + wm + mi * 16 + (lane >> 4) * 4 + r_;
            if (mrow >= M) continue;
            #pragma unroll
            for (int ni = 0; ni < 2; ++ni) {
                int col = n0 + wn + ni * 16 + l16;
                float g = acc0[mi][ni][r_], u = acc1[mi][ni][r_];
                float val = g * u / (1.f + __expf(-g));
                if (sp) Cs[(size_t)mrow * SFD + col] = f2bf(val);
                else    Cr[(size_t)(row_off + mrow) * FD + col] = f2bf(val);
            }
        }
    }
}

// =============================================================================
// gemm_down: DOWN mega, BN=256, 512 threads / 8 waves (r15) + 3-buffer
// counted-vmcnt depth-2. 3 stage instrs/thread -> vmcnt(6/3/0). LDS 72 KB.
// =============================================================================
__global__ __launch_bounds__(512, 4)
void gemm_down(const us* __restrict__ Ashared, const us* __restrict__ Arouted,
               const us* __restrict__ Bshared, const us* __restrict__ Brouted,
               float* __restrict__ Cshared, us* __restrict__ Crouted,
               const int* __restrict__ counts, const int* __restrict__ offsets) {
    __shared__ s16x8 Asl[3][512];    // 128 rows x 32k
    __shared__ s16x8 Bsl[3][1024];   // 256 rows x 32k

    int hw = blockIdx.x;
    int flat = (hw & 7) * DN_CHUNK + (hw >> 3);
    int pi = flat >> 4, mt = flat & 15;
    int grpIdx = pi / 5, pos = pi % 5;
    int z, nt;
    if (pos == 0) { z = grpIdx >> 3; nt = grpIdx & 7; }
    else { int ri = grpIdx * 4 + (pos - 1); z = 2 + (ri >> 3); nt = ri & 7; }

    bool sp = (z < 2);
    int e = z - 2;
    int M = sp ? TT : counts[e];
    int n0 = nt * 256;
    int m0 = mt * BM;
    if (M == 0 || m0 >= M) return;
    int row_off = sp ? 0 : offsets[e];
    int NT = sp ? (SFD / 2 / BK) : (FD / BK);
    int lda = sp ? SFD : FD;
    int kofs = sp ? z * (SFD / 2) : 0;
    const us* Abase = (sp ? Ashared : Arouted) + kofs;
    const us* Bbase = (sp ? Bshared : Brouted + (size_t)e * HD * FD) + kofs;

    int tid = threadIdx.x;
    int lane = tid & 63, w = tid >> 6;

    // A staging: thread covers row tid>>2 (1 instr)
    int sr = tid >> 2;
    int sc = (lane & 3) ^ ((sr >> 1) & 3);
    int ar = m0 + sr; if (ar > M - 1) ar = M - 1;
    size_t arow = sp ? (size_t)ar : (size_t)(row_off + ar);
    const us* aptr = Abase + arow * lda + sc * 8;
    // B staging: 256 rows, 2 instrs; instr j covers rows [32w+16j, +16)
    const us* bptr[2];
    #pragma unroll
    for (int j = 0; j < 2; ++j) {
        int r = 32 * w + 16 * j + (lane >> 2);
        int c = (lane & 3) ^ ((r >> 1) & 3);
        bptr[j] = Bbase + (size_t)(n0 + r) * lda + c * 8;
    }

    // wave tile: 2M x 4N -> per wave 64 rows x 64 cols
    int wm = (w >> 2) * 64, wn = (w & 3) * 64;
    int grp = lane >> 4, l16 = lane & 15;

    f32x4 acc[4][4];
    f32x4 zero = {0.f, 0.f, 0.f, 0.f};
    #pragma unroll
    for (int mi = 0; mi < 4; ++mi)
        #pragma unroll
        for (int ni = 0; ni < 4; ++ni) acc[mi][ni] = zero;

    auto stage = [&](int buf, int k0) {
        gload16(aptr + k0, (void*)&Asl[buf][16 * w * 4]);
        #pragma unroll
        for (int j = 0; j < 2; ++j)
            gload16(bptr[j] + k0, (void*)&Bsl[buf][(32 * w + 16 * j) * 4]);
    };

    stage(0, 0);
    stage(1, BK);
    for (int kt = 0; kt < NT; ++kt) {
        int cur = kt % 3;
        __builtin_amdgcn_s_barrier();
        if (kt + 2 < NT) {
            stage((kt + 2) % 3, (kt + 2) * BK);
            asm volatile("s_waitcnt vmcnt(6)" ::: "memory");
        } else if (kt + 1 < NT) {
            asm volatile("s_waitcnt vmcnt(3)" ::: "memory");
        } else {
            asm volatile("s_waitcnt vmcnt(0)" ::: "memory");
        }
        s16x8 af[4];
        #pragma unroll
        for (int mi = 0; mi < 4; ++mi) {
            int rr = wm + mi * 16 + l16;
            af[mi] = Asl[cur][rr * 4 + (grp ^ ((rr >> 1) & 3))];
        }
        #pragma unroll
        for (int ni = 0; ni < 4; ++ni) {
            int rb = wn + ni * 16 + l16;
            s16x8 bf = Bsl[cur][rb * 4 + (grp ^ ((rb >> 1) & 3))];
            #pragma unroll
            for (int mi = 0; mi < 4; ++mi)
                acc[mi][ni] = __builtin_amdgcn_mfma_f32_16x16x32_bf16(af[mi], bf, acc[mi][ni], 0, 0, 0);
        }
    }

    #pragma unroll
    for (int mi = 0; mi < 4; ++mi) {
        #pragma unroll
        for (int r_ = 0; r_ < 4; ++r_) {
            int mrow = m0 + wm + mi * 16 + (lane >> 4) * 4 + r_;
            if (mrow >= M) continue;
            #pragma unroll
            for (int ni = 0; ni < 4; ++ni) {
                int col = n0 + wn + ni * 16 + l16;
                float v = acc[mi][ni][r_];
                if (sp) Cshared[(size_t)z * TT * HD + (size_t)mrow * HD + col] = v;
                else    Crouted[(size_t)(row_off + mrow) * HD + col] = f2bf(v);
            }
        }
    }
}

// =============================================================================
// gemm4 (fallback path, round-5 proven): fp32 B staged via global_load_lds.
// =============================================================================
__device__ __forceinline__ unsigned cvt2(float a, float b) {
    union { float f; unsigned u; } va, vb; va.f = a; vb.f = b;
    unsigned ra = va.u + 0x8000u, rb = vb.u + 0x8000u;
    return (rb & 0xffff0000u) | (ra >> 16);
}
__device__ __forceinline__ s16x8 pack8(f32x4 h0, f32x4 h1) {
    union { unsigned u[4]; s16x8 s; } r;
    r.u[0] = cvt2(h0[0], h0[1]); r.u[1] = cvt2(h0[2], h0[3]);
    r.u[2] = cvt2(h1[0], h1[1]); r.u[3] = cvt2(h1[2], h1[3]);
    return r.s;
}

template<int EPI, bool GATHER>
__global__ __launch_bounds__(256, 2)
void gemm4(const us* __restrict__ A, int lda,
           const float* __restrict__ B, size_t eStrideB, int ldb, int K,
           int Mfixed, const int* __restrict__ counts, const int* __restrict__ offsets,
           const int* __restrict__ tlist, const float* __restrict__ wlist,
           us* __restrict__ C, int ldc,
           const float* __restrict__ gateval, float* __restrict__ out, int ldout) {
    __shared__ s16x8 As[3][512];
    __shared__ f32x4 Bs[3][1024];

    int e = blockIdx.z;
    int M = counts ? counts[e] : Mfixed;
    int n0 = blockIdx.x * BN;
    int m0 = blockIdx.y * BM;
    if (M == 0 || m0 >= M) return;
    int row_off = offsets ? offsets[e] : 0;
    const float* Bp = B + (size_t)e * eStrideB;

    int tid = threadIdx.x;
    int lane = tid & 63, w = tid >> 6;

    const us* aptr[2];
    #pragma unroll
    for (int j = 0; j < 2; ++j) {
        int r = 32 * w + 16 * j + (lane >> 2);
        int c = (lane & 3) ^ (r & 3);
        int ar = m0 + r; if (ar > M - 1) ar = M - 1;
        size_t grow;
        if constexpr (GATHER) grow = (size_t)tlist[e * TT + ar];
        else                  grow = (size_t)(row_off + ar);
        aptr[j] = A + grow * (size_t)lda + c * 8;
    }
    const float* bptr[4];
    #pragma unroll
    for (int j = 0; j < 4; ++j) {
        int r = 32 * w + 8 * j + (lane >> 3);
        int c = (lane & 7) ^ (r & 7);
        bptr[j] = Bp + (size_t)(n0 + r) * ldb + c * 4;
    }

    int wm = (w >> 1) * 64, wn = (w & 1) * 64;
    int grp = lane >> 4, l16 = lane & 15;

    f32x4 acc[4][4];
    f32x4 zero = {0.f, 0.f, 0.f, 0.f};
    #pragma unroll
    for (int mi = 0; mi < 4; ++mi)
        #pragma unroll
        for (int ni = 0; ni < 4; ++ni) acc[mi][ni] = zero;

    auto stage = [&](int buf, int k0) {
        #pragma unroll
        for (int j = 0; j < 2; ++j)
            gload16(aptr[j] + k0, (void*)&As[buf][(32 * w + 16 * j) * 4]);
        #pragma unroll
        for (int j = 0; j < 4; ++j)
            gload16(bptr[j] + k0, (void*)&Bs[buf][(32 * w + 8 * j) * 8]);
    };

    int NT = K / BK;
    stage(0, 0);
    stage(1, BK);
    for (int kt = 0; kt < NT; ++kt) {
        int cur = kt % 3;
        __builtin_amdgcn_s_barrier();
        if (kt + 2 < NT) {
            stage((kt + 2) % 3, (kt + 2) * BK);
            asm volatile("s_waitcnt vmcnt(12)" ::: "memory");
        } else if (kt + 1 < NT) {
            asm volatile("s_waitcnt vmcnt(6)" ::: "memory");
        } else {
            asm volatile("s_waitcnt vmcnt(0)" ::: "memory");
        }
        s16x8 af[4];
        #pragma unroll
        for (int mi = 0; mi < 4; ++mi) {
            int rr = wm + mi * 16 + l16;
            af[mi] = As[cur][rr * 4 + (grp ^ (rr & 3))];
        }
        #pragma unroll
        for (int ni = 0; ni < 4; ++ni) {
            int rb = wn + ni * 16 + l16;
            int s0 = (2 * grp) ^ (rb & 7);
            f32x4 h0 = Bs[cur][rb * 8 + s0];
            f32x4 h1 = Bs[cur][rb * 8 + (s0 ^ 1)];
            s16x8 bfr = pack8(h0, h1);
            #pragma unroll
            for (int mi = 0; mi < 4; ++mi)
                acc[mi][ni] = __builtin_amdgcn_mfma_f32_16x16x32_bf16(af[mi], bfr, acc[mi][ni], 0, 0, 0);
        }
    }

    #pragma unroll
    for (int mi = 0; mi < 4; ++mi) {
        #pragma unroll
        for (int r_ = 0; r_ < 4; ++r_) {
            int mrow = m0 + wm + mi * 16 + (lane >> 4) * 4 + r_;
            if (mrow >= M) continue;
            #pragma unroll
            for (int ni = 0; ni < 4; ++ni) {
                int col = n0 + wn + ni * 16 + l16;
                float v = acc[mi][ni][r_];
                if constexpr (EPI == 0) {
                    C[(size_t)(row_off + mrow) * ldc + col] = f2bf(v);
                } else if constexpr (EPI == 1) {
                    size_t idx = (size_t)(row_off + mrow) * ldc + col;
                    float g = bf2f(C[idx]);
                    C[idx] = f2bf(g * v / (1.f + __expf(-g)));
                } else if constexpr (EPI == 2) {
                    int tok = tlist[e * TT + mrow]; float wv = wlist[e * TT + mrow];
                    atomicAdd(out + (size_t)tok * ldout + col, wv * v);
                } else {
                    out[(size_t)mrow * ldout + col] = gateval[mrow] * v;
                }
            }
        }
    }
}

extern "C" void kernel_launch(void* const* d_in, const int* in_sizes, int n_in,
                              void* d_out, int out_size, void* d_ws, size_t ws_size,
                              hipStream_t stream) {
    const float* x    = (const float*)d_in[0];
    const float* gw   = (const float*)d_in[1];
    const float* gpw  = (const float*)d_in[2];
    const float* upw  = (const float*)d_in[3];
    const float* dpw  = (const float*)d_in[4];
    const float* sgw  = (const float*)d_in[5];
    const float* suw  = (const float*)d_in[6];
    const float* sdw  = (const float*)d_in[7];
    const float* segw = (const float*)d_in[8];
    float* out = (float*)d_out;
    char* ws = (char*)d_ws;

    int*   counts  = (int*)(ws + 0);
    int*   offsets = (int*)(ws + 64);
    int*   tlist   = (int*)(ws + 256);
    float* wlist   = (float*)(ws + 65792);
    float* gateval = (float*)(ws + 131328);
    int*   selpos  = (int*)(ws + 139520);

    hipMemsetAsync(counts, 0, 64, stream);

    // ---------------- main path: fused cvt + mega-dispatches -------------------
    size_t need_main = 301203456ull;
    if (ws_size >= need_main) {
        us* xb     = (us*)(ws + 262144);          //   8.4 MB
        us* gpw_b  = (us*)(ws + 8650752);         //  46.1 MB
        us* upw_b  = (us*)(ws + 54788096);        //  46.1 MB
        us* dpw_b  = (us*)(ws + 100925440);       //  46.1 MB
        us* sgw_b  = (us*)(ws + 147062784);       //  23.1 MB
        us* suw_b  = (us*)(ws + 170131456);       //  23.1 MB
        us* sdw_b  = (us*)(ws + 193200128);       //  23.1 MB
        us* gbuf_s = (us*)(ws + 216268800);       //  23.1 MB
        us* gbuf_r = (us*)(ws + 239337472);       //  11.5 MB
        us* robuf  = (us*)(ws + 250871808);       //  16.8 MB
        float* sdpart = (float*)(ws + 267649024); //  33.6 MB (2 fp32 partials)

        // dispatch 1: router + x/gateup-weight cvt
        router_cvt_kernel<<<dim3(512 + 35840), 256, 0, stream>>>(
            x, gw, segw, counts, tlist, wlist, gateval, selpos,
            gpw, upw, sgw, suw, gpw_b, upw_b, sgw_b, suw_b, xb);
        prefix_kernel<<<dim3(1), 64, 0, stream>>>(counts, offsets);

        // dispatch 2: FUSED gate+up mega (8-wave depth-2) + down-weight cvt
        gemm6<<<dim3(GU_TOT + GU_CVT), 512, 0, stream>>>(
            xb, sgw_b, suw_b, gpw_b, upw_b, gbuf_s, gbuf_r, counts, offsets, tlist,
            sdw, dpw, sdw_b, dpw_b);
        // dispatch 3: DOWN mega (BN=256, 8-wave depth-2)
        gemm_down<<<dim3(DN_TOT), 512, 0, stream>>>(
            gbuf_s, gbuf_r, sdw_b, dpw_b, sdpart, robuf, counts, offsets);

        combine_full<<<dim3(TT), 256, 0, stream>>>(selpos, wlist, offsets, gateval, sdpart, robuf, out);
        return;
    }

    // ---------------- fallback path (round-5, proven) --------------------------
    us* xb    = (us*)(ws + 155904);
    us* gbuf  = (us*)(ws + 8544512);
    us* robuf = (us*)(ws + 20078848);
    size_t need_fb = 20078848 + (size_t)4096 * HD * 2;

    router_kernel<<<dim3(TT / 4), 256, 0, stream>>>(x, gw, segw, counts, tlist, wlist, gateval, selpos);
    prefix_kernel<<<dim3(1), 64, 0, stream>>>(counts, offsets);
    cvt_kernel<<<dim3(TT * HD / 2048), 256, 0, stream>>>(x, xb);

    gemm4<0, false><<<dim3(SFD / BN, TT / BM, 1), 256, 0, stream>>>(
        xb, HD, sgw, 0, HD, HD, TT, nullptr, nullptr, nullptr, nullptr, gbuf, SFD, nullptr, nullptr, 0);
    gemm4<1, false><<<dim3(SFD / BN, TT / BM, 1), 256, 0, stream>>>(
        xb, HD, suw, 0, HD, HD, TT, nullptr, nullptr, nullptr, nullptr, gbuf, SFD, nullptr, nullptr, 0);
    gemm4<3, false><<<dim3(HD / BN, TT / BM, 1), 256, 0, stream>>>(
        gbuf, SFD, sdw, 0, SFD, SFD, TT, nullptr, nullptr, nullptr, nullptr, nullptr, 0, gateval, out, HD);

    gemm4<0, true><<<dim3(FD / BN, TT / BM, NE), 256, 0, stream>>>(
        xb, HD, gpw, (size_t)FD * HD, HD, HD, 0, counts, offsets, tlist, nullptr, gbuf, FD, nullptr, nullptr, 0);
    gemm4<1, true><<<dim3(FD / BN, TT / BM, NE), 256, 0, stream>>>(
        xb, HD, upw, (size_t)FD * HD, HD, HD, 0, counts, offsets, tlist, nullptr, gbuf, FD, nullptr, nullptr, 0);

    if (ws_size >= need_fb) {
        gemm4<0, false><<<dim3(HD / BN, TT / BM, NE), 256, 0, stream>>>(
            gbuf, FD, dpw, (size_t)HD * FD, FD, FD, 0, counts, offsets, nullptr, nullptr, robuf, HD, nullptr, nullptr, 0);
        combine_add<<<dim3(TT), 256, 0, stream>>>(selpos, wlist, offsets, robuf, out);
    } else {
        gemm4<2, false><<<dim3(HD / BN, TT / BM, NE), 256, 0, stream>>>(
            gbuf, FD, dpw, (size_t)HD * FD, FD, FD, 0, counts, offsets, tlist, wlist, nullptr, 0, nullptr, out, HD);
    }
}

// Round 18
// 441.865 us; speedup vs baseline: 1.0812x; 1.0072x over previous
//
#include <hip/hip_runtime.h>

#define TT 2048      // tokens (B*S)
#define HD 2048      // hidden
#define FD 1408      // per-expert ffn
#define SFD 5632     // shared ffn
#define NE 8         // experts
#define BM 128
#define BN 128
#define BK 32

using f32x4 = __attribute__((ext_vector_type(4))) float;
using s16x8 = __attribute__((ext_vector_type(8))) short;
typedef unsigned short us;

__device__ __forceinline__ us f2bf(float f) {
    union { float f; unsigned u; } v; v.f = f;
    unsigned r = v.u + 0x7fff + ((v.u >> 16) & 1);   // RNE
    return (us)(r >> 16);
}
__device__ __forceinline__ float bf2f(us u) {
    union { unsigned u; float f; } v; v.u = ((unsigned)u) << 16;
    return v.f;
}

__device__ __forceinline__ void gload16(const void* g, void* l) {
    __builtin_amdgcn_global_load_lds(
        (const __attribute__((address_space(1))) unsigned*)g,
        (__attribute__((address_space(3))) unsigned*)l, 16, 0, 0);
}

// 2048-element cvt tile (256 threads x 8)
__device__ __forceinline__ void cvt_tile(const float* __restrict__ src,
                                         us* __restrict__ dst, int blk) {
    size_t i = ((size_t)blk * 256 + threadIdx.x) * 8;
    float4 f0 = *(const float4*)(src + i);
    float4 f1 = *(const float4*)(src + i + 4);
    s16x8 v;
    v[0]=(short)f2bf(f0.x); v[1]=(short)f2bf(f0.y); v[2]=(short)f2bf(f0.z); v[3]=(short)f2bf(f0.w);
    v[4]=(short)f2bf(f1.x); v[5]=(short)f2bf(f1.y); v[6]=(short)f2bf(f1.z); v[7]=(short)f2bf(f1.w);
    *(s16x8*)(dst + i) = v;
}

// ---- standalone cvt (fallback path) -----------------------------------------
__global__ void cvt_kernel(const float* __restrict__ x, us* __restrict__ xb) {
    cvt_tile(x, xb, blockIdx.x);
}

// ---- fused dispatch-1: router (blocks 0..511) + gateup-weight/x cvt ---------
__global__ void router_cvt_kernel(const float* __restrict__ x, const float* __restrict__ gw,
                                  const float* __restrict__ segw,
                                  int* counts, int* tlist, float* wlist, float* gateval,
                                  int* selpos,
                                  const float* __restrict__ gpw, const float* __restrict__ upw,
                                  const float* __restrict__ sgw, const float* __restrict__ suw,
                                  us* gpw_b, us* upw_b, us* sgw_b, us* suw_b, us* xb) {
    int hw = blockIdx.x;
    if (hw >= 512) {
        int i = hw - 512;
        if      (i < 11264) cvt_tile(gpw, gpw_b, i);
        else if (i < 22528) cvt_tile(upw, upw_b, i - 11264);
        else if (i < 28160) cvt_tile(sgw, sgw_b, i - 22528);
        else if (i < 33792) cvt_tile(suw, suw_b, i - 28160);
        else                cvt_tile(x,   xb,    i - 33792);
        return;
    }
    int wave = threadIdx.x >> 6;
    int lane = threadIdx.x & 63;
    int t = hw * 4 + wave;
    float acc[9];
    #pragma unroll
    for (int i = 0; i < 9; ++i) acc[i] = 0.f;
    const float* xrow = x + (size_t)t * HD;
    for (int h = lane; h < HD; h += 64) {
        float xv = xrow[h];
        #pragma unroll
        for (int e = 0; e < NE; ++e) acc[e] += xv * gw[e * HD + h];
        acc[8] += xv * segw[h];
    }
    #pragma unroll
    for (int i = 0; i < 9; ++i) {
        float v = acc[i];
        #pragma unroll
        for (int s = 32; s > 0; s >>= 1) v += __shfl_xor(v, s);
        acc[i] = v;
    }
    if (lane == 0) {
        float m = acc[0];
        #pragma unroll
        for (int e = 1; e < NE; ++e) m = fmaxf(m, acc[e]);
        float p[NE], sum = 0.f;
        #pragma unroll
        for (int e = 0; e < NE; ++e) { p[e] = expf(acc[e] - m); sum += p[e]; }
        float inv = 1.f / sum;
        int b1 = 0, b2 = -1; float v1 = p[0], v2 = -1.f;
        #pragma unroll
        for (int e = 1; e < NE; ++e) {
            if (p[e] > v1) { v2 = v1; b2 = b1; v1 = p[e]; b1 = e; }
            else if (p[e] > v2) { v2 = p[e]; b2 = e; }
        }
        v1 *= inv; v2 *= inv;
        int s1 = atomicAdd(&counts[b1], 1); tlist[b1 * TT + s1] = t; wlist[b1 * TT + s1] = v1;
        int s2 = atomicAdd(&counts[b2], 1); tlist[b2 * TT + s2] = t; wlist[b2 * TT + s2] = v2;
        selpos[2 * t]     = b1 * TT + s1;
        selpos[2 * t + 1] = b2 * TT + s2;
        gateval[t] = 1.f / (1.f + expf(-acc[8]));
    }
}

// ---- router (fallback path, standalone) -------------------------------------
__global__ void router_kernel(const float* __restrict__ x, const float* __restrict__ gw,
                              const float* __restrict__ segw,
                              int* counts, int* tlist, float* wlist, float* gateval,
                              int* selpos) {
    int wave = threadIdx.x >> 6;
    int lane = threadIdx.x & 63;
    int t = blockIdx.x * 4 + wave;
    float acc[9];
    #pragma unroll
    for (int i = 0; i < 9; ++i) acc[i] = 0.f;
    const float* xrow = x + (size_t)t * HD;
    for (int h = lane; h < HD; h += 64) {
        float xv = xrow[h];
        #pragma unroll
        for (int e = 0; e < NE; ++e) acc[e] += xv * gw[e * HD + h];
        acc[8] += xv * segw[h];
    }
    #pragma unroll
    for (int i = 0; i < 9; ++i) {
        float v = acc[i];
        #pragma unroll
        for (int s = 32; s > 0; s >>= 1) v += __shfl_xor(v, s);
        acc[i] = v;
    }
    if (lane == 0) {
        float m = acc[0];
        #pragma unroll
        for (int e = 1; e < NE; ++e) m = fmaxf(m, acc[e]);
        float p[NE], sum = 0.f;
        #pragma unroll
        for (int e = 0; e < NE; ++e) { p[e] = expf(acc[e] - m); sum += p[e]; }
        float inv = 1.f / sum;
        int b1 = 0, b2 = -1; float v1 = p[0], v2 = -1.f;
        #pragma unroll
        for (int e = 1; e < NE; ++e) {
            if (p[e] > v1) { v2 = v1; b2 = b1; v1 = p[e]; b1 = e; }
            else if (p[e] > v2) { v2 = p[e]; b2 = e; }
        }
        v1 *= inv; v2 *= inv;
        int s1 = atomicAdd(&counts[b1], 1); tlist[b1 * TT + s1] = t; wlist[b1 * TT + s1] = v1;
        int s2 = atomicAdd(&counts[b2], 1); tlist[b2 * TT + s2] = t; wlist[b2 * TT + s2] = v2;
        selpos[2 * t]     = b1 * TT + s1;
        selpos[2 * t + 1] = b2 * TT + s2;
        gateval[t] = 1.f / (1.f + expf(-acc[8]));
    }
}

__global__ void prefix_kernel(const int* counts, int* offsets) {
    if (threadIdx.x == 0) {
        int s = 0;
        for (int e = 0; e < NE; ++e) { offsets[e] = s; s += counts[e]; }
    }
}

// ---- combine (main path): out = gv*(sd0+sd1) + w0*r0 + w1*r1 ----------------
__global__ void combine_full(const int* __restrict__ selpos, const float* __restrict__ wlist,
                             const int* __restrict__ offsets, const float* __restrict__ gateval,
                             const float* __restrict__ sdpart, const us* __restrict__ robuf,
                             float* __restrict__ out) {
    int t = blockIdx.x;
    int p0 = selpos[2 * t], p1 = selpos[2 * t + 1];
    float w0 = wlist[p0], w1 = wlist[p1];
    int r0 = offsets[p0 >> 11] + (p0 & (TT - 1));
    int r1 = offsets[p1 >> 11] + (p1 & (TT - 1));
    float g = gateval[t];
    int c = threadIdx.x * 8;
    const float* s0 = sdpart + (size_t)t * HD + c;
    const float* s1 = sdpart + (size_t)TT * HD + (size_t)t * HD + c;
    s16x8 a = *(const s16x8*)(robuf + (size_t)r0 * HD + c);
    s16x8 b = *(const s16x8*)(robuf + (size_t)r1 * HD + c);
    float* op = out + (size_t)t * HD + c;
    #pragma unroll
    for (int j = 0; j < 8; ++j)
        op[j] = g * (s0[j] + s1[j]) + w0 * bf2f((us)a[j]) + w1 * bf2f((us)b[j]);
}

// ---- combine (fallback path): out += w0*r0 + w1*r1 --------------------------
__global__ void combine_add(const int* __restrict__ selpos, const float* __restrict__ wlist,
                            const int* __restrict__ offsets,
                            const us* __restrict__ robuf, float* __restrict__ out) {
    int t = blockIdx.x;
    int p0 = selpos[2 * t], p1 = selpos[2 * t + 1];
    float w0 = wlist[p0], w1 = wlist[p1];
    int r0 = offsets[p0 >> 11] + (p0 & (TT - 1));
    int r1 = offsets[p1 >> 11] + (p1 & (TT - 1));
    int c = threadIdx.x * 8;
    s16x8 a = *(const s16x8*)(robuf + (size_t)r0 * HD + c);
    s16x8 b = *(const s16x8*)(robuf + (size_t)r1 * HD + c);
    float* op = out + (size_t)t * HD + c;
    #pragma unroll
    for (int j = 0; j < 8; ++j)
        op[j] += w0 * bf2f((us)a[j]) + w1 * bf2f((us)b[j]);
}

// 1-D mega grids
#define GU_TOT   2112
#define GU_CHUNK (GU_TOT / 8)
#define DN_TOT   1280
#define DN_CHUNK (DN_TOT / 8)
#define GU_CVT   16896   // trailing 256-thread cvt blocks (sdw 5632 + dpw 11264)

// =============================================================================
// gemm6: FUSED gate+up mega — r12's exact best form: 256 threads / 4 waves,
// per-wave 64x128 output (best LDS-bytes-per-FLOP shape for this kernel),
// 2-buffer __syncthreads loop, 48 KB LDS, + cvt backfill. Measured 222 us.
// =============================================================================
__global__ __launch_bounds__(256, 3)
void gemm6(const us* __restrict__ xb,
           const us* __restrict__ Bg_s, const us* __restrict__ Bu_s,
           const us* __restrict__ Bg_r, const us* __restrict__ Bu_r,
           us* __restrict__ Cs, us* __restrict__ Cr,
           const int* __restrict__ counts, const int* __restrict__ offsets,
           const int* __restrict__ tlist,
           const float* __restrict__ sdw_f, const float* __restrict__ dpw_f,
           us* sdw_b, us* dpw_b) {
    __shared__ s16x8 Asl[2][512];
    __shared__ s16x8 B0l[2][512];
    __shared__ s16x8 B1l[2][512];

    int hw = blockIdx.x;
    if (hw >= GU_TOT) {                       // cvt backfill
        int i = hw - GU_TOT;
        if (i < 5632) cvt_tile(sdw_f, sdw_b, i);
        else          cvt_tile(dpw_f, dpw_b, i - 5632);
        return;
    }
    int flat = (hw & 7) * GU_CHUNK + (hw >> 3);
    int pi = flat >> 4, mt = flat & 15;
    int grpIdx = pi / 3, pos = pi % 3;
    int z, nt;
    if (pos == 0) { z = 0; nt = grpIdx; }
    else { int ri = grpIdx * 2 + (pos - 1); z = 1 + ri / 11; nt = ri % 11; }

    bool sp = (z == 0);
    int e = z - 1;
    int M = sp ? TT : counts[e];
    int n0 = nt * BN;
    int m0 = mt * BM;
    if (M == 0 || m0 >= M) return;
    int row_off = sp ? 0 : offsets[e];
    const us* B0p = sp ? Bg_s : Bg_r + (size_t)e * FD * HD;
    const us* B1p = sp ? Bu_s : Bu_r + (size_t)e * FD * HD;

    int tid = threadIdx.x;
    int lane = tid & 63, w = tid >> 6;

    const us* aptr[2];
    const us* b0ptr[2];
    const us* b1ptr[2];
    #pragma unroll
    for (int j = 0; j < 2; ++j) {
        int r = 32 * w + 16 * j + (lane >> 2);
        int c = (lane & 3) ^ ((r >> 1) & 3);
        int ar = m0 + r; if (ar > M - 1) ar = M - 1;
        size_t arow = sp ? (size_t)ar : (size_t)tlist[e * TT + ar];
        aptr[j]  = xb + arow * HD + c * 8;
        b0ptr[j] = B0p + (size_t)(n0 + r) * HD + c * 8;
        b1ptr[j] = B1p + (size_t)(n0 + r) * HD + c * 8;
    }

    int wm = (w >> 1) * 64, wn = (w & 1) * 64;
    int grp = lane >> 4, l16 = lane & 15;

    f32x4 acc0[4][4], acc1[4][4];
    f32x4 zero = {0.f, 0.f, 0.f, 0.f};
    #pragma unroll
    for (int mi = 0; mi < 4; ++mi)
        #pragma unroll
        for (int ni = 0; ni < 4; ++ni) { acc0[mi][ni] = zero; acc1[mi][ni] = zero; }

    auto stage = [&](int buf, int k0) {
        #pragma unroll
        for (int j = 0; j < 2; ++j)
            gload16(aptr[j] + k0, (void*)&Asl[buf][(32 * w + 16 * j) * 4]);
        #pragma unroll
        for (int j = 0; j < 2; ++j)
            gload16(b0ptr[j] + k0, (void*)&B0l[buf][(32 * w + 16 * j) * 4]);
        #pragma unroll
        for (int j = 0; j < 2; ++j)
            gload16(b1ptr[j] + k0, (void*)&B1l[buf][(32 * w + 16 * j) * 4]);
    };

    stage(0, 0);
    int cur = 0;
    const int NT = HD / BK;
    for (int kt = 0; kt < NT; ++kt) {
        __syncthreads();
        if (kt + 1 < NT) stage(cur ^ 1, (kt + 1) * BK);
        s16x8 af[4];
        #pragma unroll
        for (int mi = 0; mi < 4; ++mi) {
            int rr = wm + mi * 16 + l16;
            af[mi] = Asl[cur][rr * 4 + (grp ^ ((rr >> 1) & 3))];
        }
        #pragma unroll
        for (int ni = 0; ni < 4; ++ni) {
            int rb = wn + ni * 16 + l16;
            int slot = rb * 4 + (grp ^ ((rb >> 1) & 3));
            s16x8 b0 = B0l[cur][slot];
            #pragma unroll
            for (int mi = 0; mi < 4; ++mi)
                acc0[mi][ni] = __builtin_amdgcn_mfma_f32_16x16x32_bf16(af[mi], b0, acc0[mi][ni], 0, 0, 0);
            s16x8 b1 = B1l[cur][slot];
            #pragma unroll
            for (int mi = 0; mi < 4; ++mi)
                acc1[mi][ni] = __builtin_amdgcn_mfma_f32_16x16x32_bf16(af[mi], b1, acc1[mi][ni], 0, 0, 0);
        }
        cur ^= 1;
    }

    #pragma unroll
    for (int mi = 0; mi < 4; ++mi) {
        #pragma unroll
        for (int r_ = 0; r_ < 4; ++r_) {
            int mrow = m0 + wm + mi * 16 + (lane >> 4) * 4 + r_;
            if (mrow >= M) continue;
            #pragma unroll
            for (int ni = 0; ni < 4; ++ni) {
                int col = n0 + wn + ni * 16 + l16;
                float g = acc0[mi][ni][r_], u = acc1[mi][ni][r_];
                float val = g * u / (1.f + __expf(-g));
                if (sp) Cs[(size_t)mrow * SFD + col] = f2bf(val);
                else    Cr[(size_t)(row_off + mrow) * FD + col] = f2bf(val);
            }
        }
    }
}

// =============================================================================
// gemm_down: DOWN mega — r15's exact best form: 512 threads / 8 waves,
// BN=256, per-wave 64x64, 2-buffer __syncthreads loop, 48 KB LDS. ~130 us.
// =============================================================================
__global__ __launch_bounds__(512, 4)
void gemm_down(const us* __restrict__ Ashared, const us* __restrict__ Arouted,
               const us* __restrict__ Bshared, const us* __restrict__ Brouted,
               float* __restrict__ Cshared, us* __restrict__ Crouted,
               const int* __restrict__ counts, const int* __restrict__ offsets) {
    __shared__ s16x8 Asl[2][512];    // 128 rows x 32k
    __shared__ s16x8 Bsl[2][1024];   // 256 rows x 32k

    int hw = blockIdx.x;
    int flat = (hw & 7) * DN_CHUNK + (hw >> 3);
    int pi = flat >> 4, mt = flat & 15;
    int grpIdx = pi / 5, pos = pi % 5;
    int z, nt;
    if (pos == 0) { z = grpIdx >> 3; nt = grpIdx & 7; }
    else { int ri = grpIdx * 4 + (pos - 1); z = 2 + (ri >> 3); nt = ri & 7; }

    bool sp = (z < 2);
    int e = z - 2;
    int M = sp ? TT : counts[e];
    int n0 = nt * 256;
    int m0 = mt * BM;
    if (M == 0 || m0 >= M) return;
    int row_off = sp ? 0 : offsets[e];
    int NT = sp ? (SFD / 2 / BK) : (FD / BK);
    int lda = sp ? SFD : FD;
    int kofs = sp ? z * (SFD / 2) : 0;
    const us* Abase = (sp ? Ashared : Arouted) + kofs;
    const us* Bbase = (sp ? Bshared : Brouted + (size_t)e * HD * FD) + kofs;

    int tid = threadIdx.x;
    int lane = tid & 63, w = tid >> 6;

    int sr = tid >> 2;
    int sc = (lane & 3) ^ ((sr >> 1) & 3);
    int ar = m0 + sr; if (ar > M - 1) ar = M - 1;
    size_t arow = sp ? (size_t)ar : (size_t)(row_off + ar);
    const us* aptr = Abase + arow * lda + sc * 8;
    const us* bptr[2];
    #pragma unroll
    for (int j = 0; j < 2; ++j) {
        int r = 32 * w + 16 * j + (lane >> 2);
        int c = (lane & 3) ^ ((r >> 1) & 3);
        bptr[j] = Bbase + (size_t)(n0 + r) * lda + c * 8;
    }

    int wm = (w >> 2) * 64, wn = (w & 3) * 64;
    int grp = lane >> 4, l16 = lane & 15;

    f32x4 acc[4][4];
    f32x4 zero = {0.f, 0.f, 0.f, 0.f};
    #pragma unroll
    for (int mi = 0; mi < 4; ++mi)
        #pragma unroll
        for (int ni = 0; ni < 4; ++ni) acc[mi][ni] = zero;

    auto stage = [&](int buf, int k0) {
        gload16(aptr + k0, (void*)&Asl[buf][16 * w * 4]);
        #pragma unroll
        for (int j = 0; j < 2; ++j)
            gload16(bptr[j] + k0, (void*)&Bsl[buf][(32 * w + 16 * j) * 4]);
    };

    stage(0, 0);
    int cur = 0;
    for (int kt = 0; kt < NT; ++kt) {
        __syncthreads();
        if (kt + 1 < NT) stage(cur ^ 1, (kt + 1) * BK);
        s16x8 af[4];
        #pragma unroll
        for (int mi = 0; mi < 4; ++mi) {
            int rr = wm + mi * 16 + l16;
            af[mi] = Asl[cur][rr * 4 + (grp ^ ((rr >> 1) & 3))];
        }
        #pragma unroll
        for (int ni = 0; ni < 4; ++ni) {
            int rb = wn + ni * 16 + l16;
            s16x8 bf = Bsl[cur][rb * 4 + (grp ^ ((rb >> 1) & 3))];
            #pragma unroll
            for (int mi = 0; mi < 4; ++mi)
                acc[mi][ni] = __builtin_amdgcn_mfma_f32_16x16x32_bf16(af[mi], bf, acc[mi][ni], 0, 0, 0);
        }
        cur ^= 1;
    }

    #pragma unroll
    for (int mi = 0; mi < 4; ++mi) {
        #pragma unroll
        for (int r_ = 0; r_ < 4; ++r_) {
            int mrow = m0 + wm + mi * 16 + (lane >> 4) * 4 + r_;
            if (mrow >= M) continue;
            #pragma unroll
            for (int ni = 0; ni < 4; ++ni) {
                int col = n0 + wn + ni * 16 + l16;
                float v = acc[mi][ni][r_];
                if (sp) Cshared[(size_t)z * TT * HD + (size_t)mrow * HD + col] = v;
                else    Crouted[(size_t)(row_off + mrow) * HD + col] = f2bf(v);
            }
        }
    }
}

// =============================================================================
// gemm4 (fallback path, round-5 proven): fp32 B staged via global_load_lds.
// =============================================================================
__device__ __forceinline__ unsigned cvt2(float a, float b) {
    union { float f; unsigned u; } va, vb; va.f = a; vb.f = b;
    unsigned ra = va.u + 0x8000u, rb = vb.u + 0x8000u;
    return (rb & 0xffff0000u) | (ra >> 16);
}
__device__ __forceinline__ s16x8 pack8(f32x4 h0, f32x4 h1) {
    union { unsigned u[4]; s16x8 s; } r;
    r.u[0] = cvt2(h0[0], h0[1]); r.u[1] = cvt2(h0[2], h0[3]);
    r.u[2] = cvt2(h1[0], h1[1]); r.u[3] = cvt2(h1[2], h1[3]);
    return r.s;
}

template<int EPI, bool GATHER>
__global__ __launch_bounds__(256, 2)
void gemm4(const us* __restrict__ A, int lda,
           const float* __restrict__ B, size_t eStrideB, int ldb, int K,
           int Mfixed, const int* __restrict__ counts, const int* __restrict__ offsets,
           const int* __restrict__ tlist, const float* __restrict__ wlist,
           us* __restrict__ C, int ldc,
           const float* __restrict__ gateval, float* __restrict__ out, int ldout) {
    __shared__ s16x8 As[3][512];
    __shared__ f32x4 Bs[3][1024];

    int e = blockIdx.z;
    int M = counts ? counts[e] : Mfixed;
    int n0 = blockIdx.x * BN;
    int m0 = blockIdx.y * BM;
    if (M == 0 || m0 >= M) return;
    int row_off = offsets ? offsets[e] : 0;
    const float* Bp = B + (size_t)e * eStrideB;

    int tid = threadIdx.x;
    int lane = tid & 63, w = tid >> 6;

    const us* aptr[2];
    #pragma unroll
    for (int j = 0; j < 2; ++j) {
        int r = 32 * w + 16 * j + (lane >> 2);
        int c = (lane & 3) ^ (r & 3);
        int ar = m0 + r; if (ar > M - 1) ar = M - 1;
        size_t grow;
        if constexpr (GATHER) grow = (size_t)tlist[e * TT + ar];
        else                  grow = (size_t)(row_off + ar);
        aptr[j] = A + grow * (size_t)lda + c * 8;
    }
    const float* bptr[4];
    #pragma unroll
    for (int j = 0; j < 4; ++j) {
        int r = 32 * w + 8 * j + (lane >> 3);
        int c = (lane & 7) ^ (r & 7);
        bptr[j] = Bp + (size_t)(n0 + r) * ldb + c * 4;
    }

    int wm = (w >> 1) * 64, wn = (w & 1) * 64;
    int grp = lane >> 4, l16 = lane & 15;

    f32x4 acc[4][4];
    f32x4 zero = {0.f, 0.f, 0.f, 0.f};
    #pragma unroll
    for (int mi = 0; mi < 4; ++mi)
        #pragma unroll
        for (int ni = 0; ni < 4; ++ni) acc[mi][ni] = zero;

    auto stage = [&](int buf, int k0) {
        #pragma unroll
        for (int j = 0; j < 2; ++j)
            gload16(aptr[j] + k0, (void*)&As[buf][(32 * w + 16 * j) * 4]);
        #pragma unroll
        for (int j = 0; j < 4; ++j)
            gload16(bptr[j] + k0, (void*)&Bs[buf][(32 * w + 8 * j) * 8]);
    };

    int NT = K / BK;
    stage(0, 0);
    stage(1, BK);
    for (int kt = 0; kt < NT; ++kt) {
        int cur = kt % 3;
        __builtin_amdgcn_s_barrier();
        if (kt + 2 < NT) {
            stage((kt + 2) % 3, (kt + 2) * BK);
            asm volatile("s_waitcnt vmcnt(12)" ::: "memory");
        } else if (kt + 1 < NT) {
            asm volatile("s_waitcnt vmcnt(6)" ::: "memory");
        } else {
            asm volatile("s_waitcnt vmcnt(0)" ::: "memory");
        }
        s16x8 af[4];
        #pragma unroll
        for (int mi = 0; mi < 4; ++mi) {
            int rr = wm + mi * 16 + l16;
            af[mi] = As[cur][rr * 4 + (grp ^ (rr & 3))];
        }
        #pragma unroll
        for (int ni = 0; ni < 4; ++ni) {
            int rb = wn + ni * 16 + l16;
            int s0 = (2 * grp) ^ (rb & 7);
            f32x4 h0 = Bs[cur][rb * 8 + s0];
            f32x4 h1 = Bs[cur][rb * 8 + (s0 ^ 1)];
            s16x8 bfr = pack8(h0, h1);
            #pragma unroll
            for (int mi = 0; mi < 4; ++mi)
                acc[mi][ni] = __builtin_amdgcn_mfma_f32_16x16x32_bf16(af[mi], bfr, acc[mi][ni], 0, 0, 0);
        }
    }

    #pragma unroll
    for (int mi = 0; mi < 4; ++mi) {
        #pragma unroll
        for (int r_ = 0; r_ < 4; ++r_) {
            int mrow = m0 + wm + mi * 16 + (lane >> 4) * 4 + r_;
            if (mrow >= M) continue;
            #pragma unroll
            for (int ni = 0; ni < 4; ++ni) {
                int col = n0 + wn + ni * 16 + l16;
                float v = acc[mi][ni][r_];
                if constexpr (EPI == 0) {
                    C[(size_t)(row_off + mrow) * ldc + col] = f2bf(v);
                } else if constexpr (EPI == 1) {
                    size_t idx = (size_t)(row_off + mrow) * ldc + col;
                    float g = bf2f(C[idx]);
                    C[idx] = f2bf(g * v / (1.f + __expf(-g)));
                } else if constexpr (EPI == 2) {
                    int tok = tlist[e * TT + mrow]; float wv = wlist[e * TT + mrow];
                    atomicAdd(out + (size_t)tok * ldout + col, wv * v);
                } else {
                    out[(size_t)mrow * ldout + col] = gateval[mrow] * v;
                }
            }
        }
    }
}

extern "C" void kernel_launch(void* const* d_in, const int* in_sizes, int n_in,
                              void* d_out, int out_size, void* d_ws, size_t ws_size,
                              hipStream_t stream) {
    const float* x    = (const float*)d_in[0];
    const float* gw   = (const float*)d_in[1];
    const float* gpw  = (const float*)d_in[2];
    const float* upw  = (const float*)d_in[3];
    const float* dpw  = (const float*)d_in[4];
    const float* sgw  = (const float*)d_in[5];
    const float* suw  = (const float*)d_in[6];
    const float* sdw  = (const float*)d_in[7];
    const float* segw = (const float*)d_in[8];
    float* out = (float*)d_out;
    char* ws = (char*)d_ws;

    int*   counts  = (int*)(ws + 0);
    int*   offsets = (int*)(ws + 64);
    int*   tlist   = (int*)(ws + 256);
    float* wlist   = (float*)(ws + 65792);
    float* gateval = (float*)(ws + 131328);
    int*   selpos  = (int*)(ws + 139520);

    hipMemsetAsync(counts, 0, 64, stream);

    // ---------------- main path: fused cvt + mega-dispatches -------------------
    size_t need_main = 301203456ull;
    if (ws_size >= need_main) {
        us* xb     = (us*)(ws + 262144);          //   8.4 MB
        us* gpw_b  = (us*)(ws + 8650752);         //  46.1 MB
        us* upw_b  = (us*)(ws + 54788096);        //  46.1 MB
        us* dpw_b  = (us*)(ws + 100925440);       //  46.1 MB
        us* sgw_b  = (us*)(ws + 147062784);       //  23.1 MB
        us* suw_b  = (us*)(ws + 170131456);       //  23.1 MB
        us* sdw_b  = (us*)(ws + 193200128);       //  23.1 MB
        us* gbuf_s = (us*)(ws + 216268800);       //  23.1 MB
        us* gbuf_r = (us*)(ws + 239337472);       //  11.5 MB
        us* robuf  = (us*)(ws + 250871808);       //  16.8 MB
        float* sdpart = (float*)(ws + 267649024); //  33.6 MB (2 fp32 partials)

        // dispatch 1: router + x/gateup-weight cvt
        router_cvt_kernel<<<dim3(512 + 35840), 256, 0, stream>>>(
            x, gw, segw, counts, tlist, wlist, gateval, selpos,
            gpw, upw, sgw, suw, gpw_b, upw_b, sgw_b, suw_b, xb);
        prefix_kernel<<<dim3(1), 64, 0, stream>>>(counts, offsets);

        // dispatch 2: FUSED gate+up mega (r12's 4-wave form) + down-weight cvt
        gemm6<<<dim3(GU_TOT + GU_CVT), 256, 0, stream>>>(
            xb, sgw_b, suw_b, gpw_b, upw_b, gbuf_s, gbuf_r, counts, offsets, tlist,
            sdw, dpw, sdw_b, dpw_b);
        // dispatch 3: DOWN mega (r15's 8-wave BN=256 form)
        gemm_down<<<dim3(DN_TOT), 512, 0, stream>>>(
            gbuf_s, gbuf_r, sdw_b, dpw_b, sdpart, robuf, counts, offsets);

        combine_full<<<dim3(TT), 256, 0, stream>>>(selpos, wlist, offsets, gateval, sdpart, robuf, out);
        return;
    }

    // ---------------- fallback path (round-5, proven) --------------------------
    us* xb    = (us*)(ws + 155904);
    us* gbuf  = (us*)(ws + 8544512);
    us* robuf = (us*)(ws + 20078848);
    size_t need_fb = 20078848 + (size_t)4096 * HD * 2;

    router_kernel<<<dim3(TT / 4), 256, 0, stream>>>(x, gw, segw, counts, tlist, wlist, gateval, selpos);
    prefix_kernel<<<dim3(1), 64, 0, stream>>>(counts, offsets);
    cvt_kernel<<<dim3(TT * HD / 2048), 256, 0, stream>>>(x, xb);

    gemm4<0, false><<<dim3(SFD / BN, TT / BM, 1), 256, 0, stream>>>(
        xb, HD, sgw, 0, HD, HD, TT, nullptr, nullptr, nullptr, nullptr, gbuf, SFD, nullptr, nullptr, 0);
    gemm4<1, false><<<dim3(SFD / BN, TT / BM, 1), 256, 0, stream>>>(
        xb, HD, suw, 0, HD, HD, TT, nullptr, nullptr, nullptr, nullptr, gbuf, SFD, nullptr, nullptr, 0);
    gemm4<3, false><<<dim3(HD / BN, TT / BM, 1), 256, 0, stream>>>(
        gbuf, SFD, sdw, 0, SFD, SFD, TT, nullptr, nullptr, nullptr, nullptr, nullptr, 0, gateval, out, HD);

    gemm4<0, true><<<dim3(FD / BN, TT / BM, NE), 256, 0, stream>>>(
        xb, HD, gpw, (size_t)FD * HD, HD, HD, 0, counts, offsets, tlist, nullptr, gbuf, FD, nullptr, nullptr, 0);
    gemm4<1, true><<<dim3(FD / BN, TT / BM, NE), 256, 0, stream>>>(
        xb, HD, upw, (size_t)FD * HD, HD, HD, 0, counts, offsets, tlist, nullptr, gbuf, FD, nullptr, nullptr, 0);

    if (ws_size >= need_fb) {
        gemm4<0, false><<<dim3(HD / BN, TT / BM, NE), 256, 0, stream>>>(
            gbuf, FD, dpw, (size_t)HD * FD, FD, FD, 0, counts, offsets, nullptr, nullptr, robuf, HD, nullptr, nullptr, 0);
        combine_add<<<dim3(TT), 256, 0, stream>>>(selpos, wlist, offsets, robuf, out);
    } else {
        gemm4<2, false><<<dim3(HD / BN, TT / BM, NE), 256, 0, stream>>>(
            gbuf, FD, dpw, (size_t)HD * FD, FD, FD, 0, counts, offsets, tlist, wlist, nullptr, 0, nullptr, out, HD);
    }
}